// Round 14
// baseline (250.128 us; speedup 1.0000x reference)
//
#include <hip/hip_runtime.h>

#define NN 50000
#define NE 600000
#define SCAN_BLOCKS 196  // 196*256 = 50176 >= NN

typedef short v8s __attribute__((ext_vector_type(8)));
typedef float v4f __attribute__((ext_vector_type(4)));

#define MTW 264   // mT row stride in shorts: 256 data + 8 pad

__device__ __forceinline__ float uaf(unsigned u) {
    union { unsigned u; float f; } v; v.u = u; return v.f;
}
__device__ __forceinline__ ushort f2b(float f) {
    union { float f; unsigned u; } v; v.f = f;
    unsigned r = v.u + 0x7FFFu + ((v.u >> 16) & 1u);  // RNE
    return (ushort)(r >> 16);
}

// ---------- edge-index dtype detection (int32 vs int64 storage) ----------
__global__ __launch_bounds__(256) void detect_idx_kernel(const int* __restrict__ raw,
                                                          int* __restrict__ flag) {
    __shared__ int cnt;
    if (threadIdx.x == 0) cnt = 0;
    __syncthreads();
    int c = 0;
    for (int i = threadIdx.x; i < 2048; i += 256)
        if (raw[2 * i + 1] != 0) c++;
    atomicAdd(&cnt, c);
    __syncthreads();
    if (threadIdx.x == 0) *flag = (cnt > 10) ? 1 : 0;  // 1 => int32 layout
}

// degree count directly from raw edges (dst half)
__global__ __launch_bounds__(256) void count_deg_raw_kernel(const void* __restrict__ raw,
                                                             const int* __restrict__ flag,
                                                             int* __restrict__ deg) {
    int e = blockIdx.x * 256 + threadIdx.x;
    if (e >= NE) return;
    int d;
    if (*flag) d = ((const int*)raw)[NE + e];
    else       d = (int)((const long long*)raw)[NE + e];
    atomicAdd(&deg[d], 1);
}

// ---------- hierarchical scan: deg[NN] -> rowptr[NN+1], cursor[NN] ----------
__global__ __launch_bounds__(256) void block_sum_kernel(const int* __restrict__ deg,
                                                         int* __restrict__ bsum) {
    const int i = blockIdx.x * 256 + threadIdx.x;
    int v = (i < NN) ? deg[i] : 0;
#pragma unroll
    for (int o = 32; o; o >>= 1) v += __shfl_down(v, o, 64);
    __shared__ int ws[4];
    if ((threadIdx.x & 63) == 0) ws[threadIdx.x >> 6] = v;
    __syncthreads();
    if (threadIdx.x == 0) bsum[blockIdx.x] = ws[0] + ws[1] + ws[2] + ws[3];
}

__global__ __launch_bounds__(256) void scan_sums_kernel(const int* __restrict__ bsum,
                                                         int* __restrict__ boff,
                                                         int* __restrict__ rowptr) {
    __shared__ int tmp[256];
    const int t = threadIdx.x;
    const int v = (t < SCAN_BLOCKS) ? bsum[t] : 0;
    tmp[t] = v;
    __syncthreads();
#pragma unroll
    for (int off = 1; off < 256; off <<= 1) {
        int u = (t >= off) ? tmp[t - off] : 0;
        __syncthreads();
        tmp[t] += u;
        __syncthreads();
    }
    boff[t] = tmp[t] - v;  // exclusive
    if (t == 255) rowptr[NN] = tmp[255];
}

__global__ __launch_bounds__(256) void block_scan_kernel(const int* __restrict__ deg,
                                                          const int* __restrict__ boff,
                                                          int* __restrict__ rowptr,
                                                          int* __restrict__ cursor) {
    const int t = threadIdx.x;
    const int i = blockIdx.x * 256 + t;
    const int lane = t & 63, w = t >> 6;
    const int v = (i < NN) ? deg[i] : 0;
    int s = v;
#pragma unroll
    for (int o = 1; o < 64; o <<= 1) {
        int u = __shfl_up(s, o, 64);
        if (lane >= o) s += u;
    }
    __shared__ int wsum[4];
    if (lane == 63) wsum[w] = s;
    __syncthreads();
    int wpre = 0;
    for (int k = 0; k < w; k++) wpre += wsum[k];
    const int excl = boff[blockIdx.x] + wpre + s - v;
    if (i < NN) {
        rowptr[i] = excl;
        cursor[i] = excl;
    }
}

// CSR fill directly from raw edges
__global__ __launch_bounds__(256) void fill_csr_raw_kernel(const void* __restrict__ raw,
                                                            const int* __restrict__ flag,
                                                            int* __restrict__ cursor,
                                                            int* __restrict__ csr_src) {
    int e = blockIdx.x * 256 + threadIdx.x;
    if (e >= NE) return;
    int s, d;
    if (*flag) {
        s = ((const int*)raw)[e];
        d = ((const int*)raw)[NE + e];
    } else {
        s = (int)((const long long*)raw)[e];
        d = (int)((const long long*)raw)[NE + e];
    }
    int pos = atomicAdd(&cursor[d], 1);
    csr_src[pos] = s;
}

// ---------- fp32 -> bf16 converter (x) ----------
__global__ __launch_bounds__(256) void cvt_f32_bf16_kernel(const float* __restrict__ in,
                                                            ushort* __restrict__ out, int n4) {
    int i = blockIdx.x * 256 + threadIdx.x;
    if (i >= n4) return;
    const float4 v = *(const float4*)&in[(size_t)i * 4];
    ushort4 o;
    o.x = f2b(v.x); o.y = f2b(v.y); o.z = f2b(v.z); o.w = f2b(v.w);
    *(ushort4*)&out[(size_t)i * 4] = o;
}

// ---------- merged fragment-major weight packing ----------
// blocks [0,128): w1a (K1=128); [128,384): w2a; [384,640): w1b (as stage-1, K1=256);
// [640,656): w2b head.
__device__ __forceinline__ void pack_w1_elem(const float* in, ushort* out, int o, int K1) {
    int j = o & 7, lane = (o >> 3) & 63, f = o >> 9;
    int kk = f & 1, n = (f >> 1) & 3, wv = (f >> 3) & 3, s = f >> 5;
    int k = s * 64 + kk * 32 + (lane >> 4) * 8 + j;
    int col = wv * 64 + n * 16 + (lane & 15);
    out[o] = f2b(in[(size_t)k * 256 + col]);
}
__global__ __launch_bounds__(256) void pack_all_kernel(const float* __restrict__ w1a,
                                                        const float* __restrict__ w2a,
                                                        const float* __restrict__ w1b,
                                                        const float* __restrict__ wh,
                                                        ushort* __restrict__ W1pa,
                                                        ushort* __restrict__ W2pa,
                                                        ushort* __restrict__ W1pb,
                                                        ushort* __restrict__ W2hp) {
    const int b = blockIdx.x;
    if (b < 128) {
        pack_w1_elem(w1a, W1pa, b * 256 + threadIdx.x, 128);
    } else if (b < 384) {
        int o = (b - 128) * 256 + threadIdx.x;
        int j = o & 7, lane = (o >> 3) & 63, f = o >> 9;
        int kk = f & 3, n = (f >> 2) & 3, wv = (f >> 4) & 3, kh = f >> 6;
        int k = kh * 128 + kk * 32 + (lane >> 4) * 8 + j;
        int col = wv * 64 + n * 16 + (lane & 15);
        W2pa[o] = f2b(w2a[(size_t)k * 256 + col]);
    } else if (b < 640) {
        pack_w1_elem(w1b, W1pb, (b - 384) * 256 + threadIdx.x, 256);
    } else {
        int o = (b - 640) * 256 + threadIdx.x;
        int j = o & 7, lane = (o >> 3) & 63, k8 = o >> 9;
        int k = k8 * 32 + (lane >> 4) * 8 + j;
        int col = lane & 15;
        W2hp[o] = f2b(wh[(size_t)k * 16 + col]);
    }
}

// ---------- fused GIN conv: aggregate + 2-layer MLP (+ optional head) ----------
// Block: 64 nodes, 4 waves. Phase A: each wave aggregates 16 nodes (wave-uniform
// node -> scalar index loads; 8 gathers in flight) into LDS zT (bf16, identical
// numerics to the standalone aggregate). One barrier, then stage-1 MFMA reads
// A-frags from zT, W1 from frag-major packed global (contiguous 1KB wave-bursts).
// Stage-2 / head identical to round-12 (frag-major W2, mT staging, blit epilogue).
template <int K1, bool HEAD>
__global__ __launch_bounds__(256) void fused_gin_kernel(const ushort* __restrict__ feat,
                                                         const int* __restrict__ rowptr,
                                                         const int* __restrict__ csr_src,
                                                         const ushort* __restrict__ W1p,
                                                         const float* __restrict__ b1,
                                                         const ushort* __restrict__ W2p,
                                                         const float* __restrict__ b2,
                                                         void* __restrict__ outp, int M) {
    constexpr int S = K1 / 64;          // stage-1 k-steps
    constexpr int ZW = K1 + 8;          // zT row stride
    __shared__ ushort zT[64 * ZW];      // conv1 17.4 KB / conv2 33.8 KB
    __shared__ ushort mT[64 * MTW];     // 33.8 KB
    const int tid = threadIdx.x;
    const int lane = tid & 63;
    const int wv = tid >> 6;
    const int row0 = blockIdx.x * 64;
    const int l15 = lane & 15;
    const int kq = lane >> 4;

    // ---- Phase A: aggregate z = feat[node] + sum feat[neighbors] -> zT ----
    for (int t = 0; t < 16; t++) {
        const int r = wv * 16 + t;
        const int node = __builtin_amdgcn_readfirstlane(row0 + r);
        ushort* zrow = &zT[r * ZW];
        if (node < M) {
            const int rbeg = rowptr[node];
            const int rend = rowptr[node + 1];
            if constexpr (K1 == 256) {
                const uint2 sv = *(const uint2*)&feat[(size_t)node * 256 + lane * 4];
                float a0 = uaf(sv.x << 16), a1 = uaf(sv.x & 0xFFFF0000u);
                float a2 = uaf(sv.y << 16), a3 = uaf(sv.y & 0xFFFF0000u);
                int j = rbeg;
                for (; j + 7 < rend; j += 8) {
                    uint2 v[8];
#pragma unroll
                    for (int q = 0; q < 8; q++)
                        v[q] = *(const uint2*)&feat[(size_t)csr_src[j + q] * 256 + lane * 4];
#pragma unroll
                    for (int q = 0; q < 8; q++) {
                        a0 += uaf(v[q].x << 16); a1 += uaf(v[q].x & 0xFFFF0000u);
                        a2 += uaf(v[q].y << 16); a3 += uaf(v[q].y & 0xFFFF0000u);
                    }
                }
                for (; j + 3 < rend; j += 4) {
                    uint2 v[4];
#pragma unroll
                    for (int q = 0; q < 4; q++)
                        v[q] = *(const uint2*)&feat[(size_t)csr_src[j + q] * 256 + lane * 4];
#pragma unroll
                    for (int q = 0; q < 4; q++) {
                        a0 += uaf(v[q].x << 16); a1 += uaf(v[q].x & 0xFFFF0000u);
                        a2 += uaf(v[q].y << 16); a3 += uaf(v[q].y & 0xFFFF0000u);
                    }
                }
                for (; j < rend; j++) {
                    const uint2 v = *(const uint2*)&feat[(size_t)csr_src[j] * 256 + lane * 4];
                    a0 += uaf(v.x << 16); a1 += uaf(v.x & 0xFFFF0000u);
                    a2 += uaf(v.y << 16); a3 += uaf(v.y & 0xFFFF0000u);
                }
                uint2 o;
                o.x = (uint)f2b(a0) | ((uint)f2b(a1) << 16);
                o.y = (uint)f2b(a2) | ((uint)f2b(a3) << 16);
                *(uint2*)&zrow[lane * 4] = o;
            } else {  // K1 == 128
                const uint sv = *(const uint*)&feat[(size_t)node * 128 + lane * 2];
                float a0 = uaf(sv << 16), a1 = uaf(sv & 0xFFFF0000u);
                int j = rbeg;
                for (; j + 7 < rend; j += 8) {
                    uint v[8];
#pragma unroll
                    for (int q = 0; q < 8; q++)
                        v[q] = *(const uint*)&feat[(size_t)csr_src[j + q] * 128 + lane * 2];
#pragma unroll
                    for (int q = 0; q < 8; q++) {
                        a0 += uaf(v[q] << 16); a1 += uaf(v[q] & 0xFFFF0000u);
                    }
                }
                for (; j + 3 < rend; j += 4) {
                    uint v[4];
#pragma unroll
                    for (int q = 0; q < 4; q++)
                        v[q] = *(const uint*)&feat[(size_t)csr_src[j + q] * 128 + lane * 2];
#pragma unroll
                    for (int q = 0; q < 4; q++) {
                        a0 += uaf(v[q] << 16); a1 += uaf(v[q] & 0xFFFF0000u);
                    }
                }
                for (; j < rend; j++) {
                    const uint v = *(const uint*)&feat[(size_t)csr_src[j] * 128 + lane * 2];
                    a0 += uaf(v << 16); a1 += uaf(v & 0xFFFF0000u);
                }
                *(uint*)&zrow[lane * 2] = (uint)f2b(a0) | ((uint)f2b(a1) << 16);
            }
        } else {
            if constexpr (K1 == 256) *(uint2*)&zrow[lane * 4] = (uint2){0u, 0u};
            else                     *(uint*)&zrow[lane * 2] = 0u;
        }
    }
    __syncthreads();  // zT ready

    // ---- stage 1: m = relu(z @ W1 + b1), barrier-free ----
    v4f acc[4][4];
#pragma unroll
    for (int m = 0; m < 4; m++)
#pragma unroll
        for (int n = 0; n < 4; n++) acc[m][n] = (v4f){0.f, 0.f, 0.f, 0.f};
#pragma unroll
    for (int s = 0; s < S; s++) {
        v8s w1r[4][2];
#pragma unroll
        for (int n = 0; n < 4; n++)
#pragma unroll
            for (int kk = 0; kk < 2; kk++)
                w1r[n][kk] = *(const v8s*)(W1p + (size_t)(s * 32 + wv * 8 + n * 2 + kk) * 512 + lane * 8);
        v8s af[4][2];
#pragma unroll
        for (int m = 0; m < 4; m++)
#pragma unroll
            for (int kk = 0; kk < 2; kk++)
                af[m][kk] = *(const v8s*)&zT[(m * 16 + l15) * ZW + s * 64 + kk * 32 + kq * 8];
#pragma unroll
        for (int kk = 0; kk < 2; kk++)
#pragma unroll
            for (int m = 0; m < 4; m++)
#pragma unroll
                for (int n = 0; n < 4; n++)
                    acc[m][n] = __builtin_amdgcn_mfma_f32_16x16x32_bf16(af[m][kk], w1r[n][kk], acc[m][n], 0, 0, 0);
    }

    // ---- stage-1 epilogue: bias + relu -> mT (bf16) ----
#pragma unroll
    for (int n = 0; n < 4; n++) {
        const int gc = wv * 64 + n * 16 + l15;
        const float bv = b1[gc];
#pragma unroll
        for (int m = 0; m < 4; m++)
#pragma unroll
            for (int r = 0; r < 4; r++)
                mT[(m * 16 + kq * 4 + r) * MTW + gc] = f2b(fmaxf(acc[m][n][r] + bv, 0.f));
    }
    __syncthreads();  // mT ready

    if constexpr (!HEAD) {
        // ---- stage 2: C = relu(m @ W2 + b2), barrier-free MFMA ----
#pragma unroll
        for (int m = 0; m < 4; m++)
#pragma unroll
            for (int n = 0; n < 4; n++) acc[m][n] = (v4f){0.f, 0.f, 0.f, 0.f};
#pragma unroll
        for (int kh = 0; kh < 2; kh++) {
            v8s w2r[4][4];
#pragma unroll
            for (int n = 0; n < 4; n++)
#pragma unroll
                for (int kk = 0; kk < 4; kk++)
                    w2r[n][kk] = *(const v8s*)(W2p + (size_t)(kh * 64 + wv * 16 + n * 4 + kk) * 512 + lane * 8);
#pragma unroll
            for (int kk = 0; kk < 4; kk++) {
                v8s a2[4];
#pragma unroll
                for (int m = 0; m < 4; m++)
                    a2[m] = *(const v8s*)&mT[(m * 16 + l15) * MTW + kh * 128 + kk * 32 + kq * 8];
#pragma unroll
                for (int m = 0; m < 4; m++)
#pragma unroll
                    for (int n = 0; n < 4; n++)
                        acc[m][n] = __builtin_amdgcn_mfma_f32_16x16x32_bf16(a2[m], w2r[n][kk], acc[m][n], 0, 0, 0);
            }
        }
        __syncthreads();  // all mT reads done before overwrite
#pragma unroll
        for (int n = 0; n < 4; n++) {
            const int gc = wv * 64 + n * 16 + l15;
            const float bv = b2[gc];
#pragma unroll
            for (int m = 0; m < 4; m++)
#pragma unroll
                for (int r = 0; r < 4; r++)
                    mT[(m * 16 + kq * 4 + r) * MTW + gc] = f2b(fmaxf(acc[m][n][r] + bv, 0.f));
        }
        __syncthreads();
        // coalesced blit: thread t -> 16B at row i*8+(t>>5), col (t&31)*8
        ushort* C = (ushort*)outp;
        const int brow = tid >> 5, bcol = (tid & 31) * 8;
#pragma unroll
        for (int i = 0; i < 8; i++) {
            const int row = i * 8 + brow;
            if (row0 + row < M) {
                const v8s v = *(const v8s*)&mT[row * MTW + bcol];
                *(v8s*)&C[(size_t)(row0 + row) * 256 + bcol] = v;
            }
        }
    } else {
        // ---- stage 2 head: o = m @ W2b + b2 (16 cols), log_softmax, fp32 out ----
        v4f h = (v4f){0.f, 0.f, 0.f, 0.f};
        v8s w2r[8];
#pragma unroll
        for (int k8 = 0; k8 < 8; k8++)
            w2r[k8] = *(const v8s*)(W2p + (size_t)k8 * 512 + lane * 8);
#pragma unroll
        for (int k8 = 0; k8 < 8; k8++) {
            const v8s a2 = *(const v8s*)&mT[(wv * 16 + l15) * MTW + k8 * 32 + kq * 8];
            h = __builtin_amdgcn_mfma_f32_16x16x32_bf16(a2, w2r[k8], h, 0, 0, 0);
        }
        float* O = (float*)outp;
        const float bv = b2[l15];
#pragma unroll
        for (int r = 0; r < 4; r++) {
            const float v = h[r] + bv;
            float mx = v;
#pragma unroll
            for (int o = 8; o; o >>= 1) mx = fmaxf(mx, __shfl_xor(mx, o, 16));
            const float e = expf(v - mx);
            float sl = e;
#pragma unroll
            for (int o = 8; o; o >>= 1) sl += __shfl_xor(sl, o, 16);
            const int grow = row0 + wv * 16 + kq * 4 + r;
            if (grow < M) O[(size_t)grow * 16 + l15] = (v - mx) - logf(sl);
        }
    }
}

extern "C" void kernel_launch(void* const* d_in, const int* in_sizes, int n_in,
                              void* d_out, int out_size, void* d_ws, size_t ws_size,
                              hipStream_t stream) {
    (void)in_sizes; (void)n_in; (void)out_size; (void)ws_size;
    const float* x   = (const float*)d_in[0];
    const void*  ei  = d_in[1];
    const float* w1a = (const float*)d_in[2];
    const float* b1a = (const float*)d_in[3];
    const float* w2a = (const float*)d_in[4];
    const float* b2a = (const float*)d_in[5];
    const float* w1b = (const float*)d_in[6];
    const float* b1b = (const float*)d_in[7];
    const float* w2b = (const float*)d_in[8];
    const float* b2b = (const float*)d_in[9];
    float* out = (float*)d_out;

    // ws layout (ushort region first, then ints)
    ushort* XB   = (ushort*)d_ws;                 // [NN][128] bf16: x
    ushort* H1   = XB + (size_t)NN * 128;         // [NN][256] bf16: h1
    ushort* W1pa = H1 + (size_t)NN * 256;         // 128*256 packed
    ushort* W2pa = W1pa + 128 * 256;              // 256*256 packed
    ushort* W1pb = W2pa + 256 * 256;              // 256*256 packed
    ushort* W2hp = W1pb + 256 * 256;              // 16*256 packed
    int* flag    = (int*)(W2hp + 16 * 256);
    int* deg     = flag + 1;                      // NN
    int* rowptr  = deg + NN;                      // NN+1
    int* cursor  = rowptr + NN + 1;               // NN
    int* csr_src = cursor + NN;                   // NE
    int* bsum    = csr_src + NE;                  // SCAN_BLOCKS
    int* boff    = bsum + SCAN_BLOCKS;            // 256

    // ---- CSR build directly from raw edge index ----
    detect_idx_kernel<<<1, 256, 0, stream>>>((const int*)ei, flag);
    hipMemsetAsync(deg, 0, NN * sizeof(int), stream);
    count_deg_raw_kernel<<<(NE + 255) / 256, 256, 0, stream>>>(ei, flag, deg);
    block_sum_kernel<<<SCAN_BLOCKS, 256, 0, stream>>>(deg, bsum);
    scan_sums_kernel<<<1, 256, 0, stream>>>(bsum, boff, rowptr);
    block_scan_kernel<<<SCAN_BLOCKS, 256, 0, stream>>>(deg, boff, rowptr, cursor);
    fill_csr_raw_kernel<<<(NE + 255) / 256, 256, 0, stream>>>(ei, flag, cursor, csr_src);

    // ---- bf16 conversion (x) + merged weight packing ----
    cvt_f32_bf16_kernel<<<(NN * 128 / 4 + 255) / 256, 256, 0, stream>>>(x, XB, NN * 128 / 4);
    pack_all_kernel<<<656, 256, 0, stream>>>(w1a, w2a, w1b, w2b, W1pa, W2pa, W1pb, W2hp);

    const int ginBlocks = (NN + 63) / 64;  // 782

    // ---- conv1: fused aggregate + MLP (x -> h1) ----
    fused_gin_kernel<128, false><<<ginBlocks, 256, 0, stream>>>(
        XB, rowptr, csr_src, W1pa, b1a, W2pa, b2a, H1, NN);

    // ---- conv2: fused aggregate + MLP + head (h1 -> out) ----
    fused_gin_kernel<256, true><<<ginBlocks, 256, 0, stream>>>(
        H1, rowptr, csr_src, W1pb, b1b, W2hp, b2b, out, NN);
}

// Round 15
// 192.013 us; speedup vs baseline: 1.3027x; 1.3027x over previous
//
#include <hip/hip_runtime.h>

#define NN 50000
#define NE 600000
#define SCAN_BLOCKS 196  // 196*256 = 50176 >= NN

typedef short v8s __attribute__((ext_vector_type(8)));
typedef float v4f __attribute__((ext_vector_type(4)));

#define LAW 72    // lA row stride in shorts: 64 data + 8 pad
#define MTW 264   // mT row stride in shorts: 256 data + 8 pad

__device__ __forceinline__ float uaf(unsigned u) {
    union { unsigned u; float f; } v; v.u = u; return v.f;
}
__device__ __forceinline__ ushort f2b(float f) {
    union { float f; unsigned u; } v; v.f = f;
    unsigned r = v.u + 0x7FFFu + ((v.u >> 16) & 1u);  // RNE
    return (ushort)(r >> 16);
}

// ---------- edge-index dtype detection (int32 vs int64 storage) ----------
__global__ __launch_bounds__(256) void detect_idx_kernel(const int* __restrict__ raw,
                                                          int* __restrict__ flag) {
    __shared__ int cnt;
    if (threadIdx.x == 0) cnt = 0;
    __syncthreads();
    int c = 0;
    for (int i = threadIdx.x; i < 2048; i += 256)
        if (raw[2 * i + 1] != 0) c++;
    atomicAdd(&cnt, c);
    __syncthreads();
    if (threadIdx.x == 0) *flag = (cnt > 10) ? 1 : 0;  // 1 => int32 layout
}

// degree count directly from raw edges (dst half)
__global__ __launch_bounds__(256) void count_deg_raw_kernel(const void* __restrict__ raw,
                                                             const int* __restrict__ flag,
                                                             int* __restrict__ deg) {
    int e = blockIdx.x * 256 + threadIdx.x;
    if (e >= NE) return;
    int d;
    if (*flag) d = ((const int*)raw)[NE + e];
    else       d = (int)((const long long*)raw)[NE + e];
    atomicAdd(&deg[d], 1);
}

// ---------- hierarchical scan: deg[NN] -> rowptr[NN+1], cursor[NN] ----------
__global__ __launch_bounds__(256) void block_sum_kernel(const int* __restrict__ deg,
                                                         int* __restrict__ bsum) {
    const int i = blockIdx.x * 256 + threadIdx.x;
    int v = (i < NN) ? deg[i] : 0;
#pragma unroll
    for (int o = 32; o; o >>= 1) v += __shfl_down(v, o, 64);
    __shared__ int ws[4];
    if ((threadIdx.x & 63) == 0) ws[threadIdx.x >> 6] = v;
    __syncthreads();
    if (threadIdx.x == 0) bsum[blockIdx.x] = ws[0] + ws[1] + ws[2] + ws[3];
}

__global__ __launch_bounds__(256) void scan_sums_kernel(const int* __restrict__ bsum,
                                                         int* __restrict__ boff,
                                                         int* __restrict__ rowptr) {
    __shared__ int tmp[256];
    const int t = threadIdx.x;
    const int v = (t < SCAN_BLOCKS) ? bsum[t] : 0;
    tmp[t] = v;
    __syncthreads();
#pragma unroll
    for (int off = 1; off < 256; off <<= 1) {
        int u = (t >= off) ? tmp[t - off] : 0;
        __syncthreads();
        tmp[t] += u;
        __syncthreads();
    }
    boff[t] = tmp[t] - v;  // exclusive
    if (t == 255) rowptr[NN] = tmp[255];
}

__global__ __launch_bounds__(256) void block_scan_kernel(const int* __restrict__ deg,
                                                          const int* __restrict__ boff,
                                                          int* __restrict__ rowptr,
                                                          int* __restrict__ cursor) {
    const int t = threadIdx.x;
    const int i = blockIdx.x * 256 + t;
    const int lane = t & 63, w = t >> 6;
    const int v = (i < NN) ? deg[i] : 0;
    int s = v;
#pragma unroll
    for (int o = 1; o < 64; o <<= 1) {
        int u = __shfl_up(s, o, 64);
        if (lane >= o) s += u;
    }
    __shared__ int wsum[4];
    if (lane == 63) wsum[w] = s;
    __syncthreads();
    int wpre = 0;
    for (int k = 0; k < w; k++) wpre += wsum[k];
    const int excl = boff[blockIdx.x] + wpre + s - v;
    if (i < NN) {
        rowptr[i] = excl;
        cursor[i] = excl;
    }
}

// CSR fill directly from raw edges
__global__ __launch_bounds__(256) void fill_csr_raw_kernel(const void* __restrict__ raw,
                                                            const int* __restrict__ flag,
                                                            int* __restrict__ cursor,
                                                            int* __restrict__ csr_src) {
    int e = blockIdx.x * 256 + threadIdx.x;
    if (e >= NE) return;
    int s, d;
    if (*flag) {
        s = ((const int*)raw)[e];
        d = ((const int*)raw)[NE + e];
    } else {
        s = (int)((const long long*)raw)[e];
        d = (int)((const long long*)raw)[NE + e];
    }
    int pos = atomicAdd(&cursor[d], 1);
    csr_src[pos] = s;
}

// ---------- merged prep: x -> bf16 + fragment-major weight packing ----------
// blocks [0, XCVT): x cvt (float4/thread); then w1a(128) | w2a(256) | w1b(256) | wh(16).
#define XCVT (NN * 128 / 4 / 256)  // 6250
__device__ __forceinline__ void pack_w1_elem(const float* in, ushort* out, int o) {
    int j = o & 7, lane = (o >> 3) & 63, f = o >> 9;
    int kk = f & 1, n = (f >> 1) & 3, wv = (f >> 3) & 3, s = f >> 5;
    int k = s * 64 + kk * 32 + (lane >> 4) * 8 + j;
    int col = wv * 64 + n * 16 + (lane & 15);
    out[o] = f2b(in[(size_t)k * 256 + col]);
}
__global__ __launch_bounds__(256) void prep_kernel(const float* __restrict__ x,
                                                    ushort* __restrict__ XB,
                                                    const float* __restrict__ w1a,
                                                    const float* __restrict__ w2a,
                                                    const float* __restrict__ w1b,
                                                    const float* __restrict__ wh,
                                                    ushort* __restrict__ W1pa,
                                                    ushort* __restrict__ W2pa,
                                                    ushort* __restrict__ W1pb,
                                                    ushort* __restrict__ W2hp) {
    const int b = blockIdx.x;
    if (b < XCVT) {
        const int i = b * 256 + threadIdx.x;
        const float4 v = *(const float4*)&x[(size_t)i * 4];
        ushort4 o;
        o.x = f2b(v.x); o.y = f2b(v.y); o.z = f2b(v.z); o.w = f2b(v.w);
        *(ushort4*)&XB[(size_t)i * 4] = o;
    } else if (b < XCVT + 128) {
        pack_w1_elem(w1a, W1pa, (b - XCVT) * 256 + threadIdx.x);
    } else if (b < XCVT + 384) {
        int o = (b - XCVT - 128) * 256 + threadIdx.x;
        int j = o & 7, lane = (o >> 3) & 63, f = o >> 9;
        int kk = f & 3, n = (f >> 2) & 3, wv = (f >> 4) & 3, kh = f >> 6;
        int k = kh * 128 + kk * 32 + (lane >> 4) * 8 + j;
        int col = wv * 64 + n * 16 + (lane & 15);
        W2pa[o] = f2b(w2a[(size_t)k * 256 + col]);
    } else if (b < XCVT + 640) {
        pack_w1_elem(w1b, W1pb, (b - XCVT - 384) * 256 + threadIdx.x);
    } else {
        int o = (b - XCVT - 640) * 256 + threadIdx.x;
        int j = o & 7, lane = (o >> 3) & 63, k8 = o >> 9;
        int k = k8 * 32 + (lane >> 4) * 8 + j;
        int col = lane & 15;
        W2hp[o] = f2b(wh[(size_t)k * 16 + col]);
    }
}

// ---------- gather-aggregate v2: scalar index path, 8 gathers in flight ----------
template <int D>
__global__ __launch_bounds__(256) void aggregate_bf16_kernel(const ushort* __restrict__ feat,
                                                              ushort* __restrict__ z,
                                                              const int* __restrict__ rowptr,
                                                              const int* __restrict__ csr_src) {
    const int node = __builtin_amdgcn_readfirstlane(blockIdx.x * 4 + (threadIdx.x >> 6));
    const int lane = threadIdx.x & 63;
    if (node >= NN) return;
    const int rbeg = rowptr[node];
    const int rend = rowptr[node + 1];

    if constexpr (D == 256) {
        const size_t base = (size_t)node * 256 + lane * 4;
        const uint2 sv = *(const uint2*)&feat[base];
        float a0 = uaf(sv.x << 16), a1 = uaf(sv.x & 0xFFFF0000u);
        float a2 = uaf(sv.y << 16), a3 = uaf(sv.y & 0xFFFF0000u);
        int j = rbeg;
        for (; j + 7 < rend; j += 8) {
            uint2 v[8];
#pragma unroll
            for (int q = 0; q < 8; q++)
                v[q] = *(const uint2*)&feat[(size_t)csr_src[j + q] * 256 + lane * 4];
#pragma unroll
            for (int q = 0; q < 8; q++) {
                a0 += uaf(v[q].x << 16); a1 += uaf(v[q].x & 0xFFFF0000u);
                a2 += uaf(v[q].y << 16); a3 += uaf(v[q].y & 0xFFFF0000u);
            }
        }
        for (; j + 3 < rend; j += 4) {
            uint2 v[4];
#pragma unroll
            for (int q = 0; q < 4; q++)
                v[q] = *(const uint2*)&feat[(size_t)csr_src[j + q] * 256 + lane * 4];
#pragma unroll
            for (int q = 0; q < 4; q++) {
                a0 += uaf(v[q].x << 16); a1 += uaf(v[q].x & 0xFFFF0000u);
                a2 += uaf(v[q].y << 16); a3 += uaf(v[q].y & 0xFFFF0000u);
            }
        }
        for (; j < rend; j++) {
            const uint2 v = *(const uint2*)&feat[(size_t)csr_src[j] * 256 + lane * 4];
            a0 += uaf(v.x << 16); a1 += uaf(v.x & 0xFFFF0000u);
            a2 += uaf(v.y << 16); a3 += uaf(v.y & 0xFFFF0000u);
        }
        uint2 o;
        o.x = (uint)f2b(a0) | ((uint)f2b(a1) << 16);
        o.y = (uint)f2b(a2) | ((uint)f2b(a3) << 16);
        *(uint2*)&z[base] = o;
    } else {  // D == 128
        const size_t base = (size_t)node * 128 + lane * 2;
        const uint sv = *(const uint*)&feat[base];
        float a0 = uaf(sv << 16), a1 = uaf(sv & 0xFFFF0000u);
        int j = rbeg;
        for (; j + 7 < rend; j += 8) {
            uint v[8];
#pragma unroll
            for (int q = 0; q < 8; q++)
                v[q] = *(const uint*)&feat[(size_t)csr_src[j + q] * 128 + lane * 2];
#pragma unroll
            for (int q = 0; q < 8; q++) {
                a0 += uaf(v[q] << 16); a1 += uaf(v[q] & 0xFFFF0000u);
            }
        }
        for (; j + 3 < rend; j += 4) {
            uint v[4];
#pragma unroll
            for (int q = 0; q < 4; q++)
                v[q] = *(const uint*)&feat[(size_t)csr_src[j + q] * 128 + lane * 2];
#pragma unroll
            for (int q = 0; q < 4; q++) {
                a0 += uaf(v[q] << 16); a1 += uaf(v[q] & 0xFFFF0000u);
            }
        }
        for (; j < rend; j++) {
            const uint v = *(const uint*)&feat[(size_t)csr_src[j] * 128 + lane * 2];
            a0 += uaf(v << 16); a1 += uaf(v & 0xFFFF0000u);
        }
        *(uint*)&z[base] = (uint)f2b(a0) | ((uint)f2b(a1) << 16);
    }
}

// ---------- fused 2-layer MLP v5: frag-major W + blit epilogue (round-12/13) ----------
template <int K1, bool HEAD>
__global__ __launch_bounds__(256) void fused_mlp_kernel(const ushort* __restrict__ A,
                                                         const ushort* __restrict__ W1p,
                                                         const float* __restrict__ b1,
                                                         const ushort* __restrict__ W2p,
                                                         const float* __restrict__ b2,
                                                         void* __restrict__ outp, int M) {
    constexpr int S = K1 / 64;          // stage-1 k-steps
    __shared__ ushort lA[2][64 * LAW];  // 18.4 KB dbuf A k-tile [64][64]
    __shared__ ushort mT[64 * MTW];     // 33.8 KB stage-1 output [64][256] bf16
    const int tid = threadIdx.x;
    const int lane = tid & 63;
    const int wv = tid >> 6;
    const int row0 = blockIdx.x * 64;
    const int l15 = lane & 15;
    const int kq = lane >> 4;
    const int ar = tid >> 2, ak = (tid & 3) * 16;  // A staging: row, k-chunk

    const bool aok = (row0 + ar) < M;
    const ushort* Arow = A + (size_t)(row0 + ar) * K1 + ak;

    v4f acc[4][4];
#pragma unroll
    for (int m = 0; m < 4; m++)
#pragma unroll
        for (int n = 0; n < 4; n++) acc[m][n] = (v4f){0.f, 0.f, 0.f, 0.f};

    v8s a0 = {}, a1v = {};
    v8s w1cur[4][2], w1nxt[4][2];

    // ---- prologue: step-0 A + W1 (contiguous frag loads) ----
    if (aok) { a0 = *(const v8s*)Arow; a1v = *(const v8s*)(Arow + 8); }
#pragma unroll
    for (int n = 0; n < 4; n++)
#pragma unroll
        for (int kk = 0; kk < 2; kk++)
            w1cur[n][kk] = *(const v8s*)(W1p + (size_t)(wv * 8 + n * 2 + kk) * 512 + lane * 8);
    *(v8s*)&lA[0][ar * LAW + ak]     = a0;
    *(v8s*)&lA[0][ar * LAW + ak + 8] = a1v;

    // ---- stage 1: m = relu(A @ W1 + b1) ----
#pragma unroll
    for (int s = 0; s < S; s++) {
        __syncthreads();
        if (s + 1 < S) {
            a0 = (v8s){}; a1v = (v8s){};
            if (aok) {
                a0  = *(const v8s*)(Arow + (s + 1) * 64);
                a1v = *(const v8s*)(Arow + (s + 1) * 64 + 8);
            }
#pragma unroll
            for (int n = 0; n < 4; n++)
#pragma unroll
                for (int kk = 0; kk < 2; kk++)
                    w1nxt[n][kk] = *(const v8s*)(W1p + (size_t)((s + 1) * 32 + wv * 8 + n * 2 + kk) * 512 + lane * 8);
        }
        v8s af[4][2];
#pragma unroll
        for (int m = 0; m < 4; m++)
#pragma unroll
            for (int kk = 0; kk < 2; kk++)
                af[m][kk] = *(const v8s*)&lA[s & 1][(m * 16 + l15) * LAW + kk * 32 + kq * 8];
#pragma unroll
        for (int kk = 0; kk < 2; kk++)
#pragma unroll
            for (int m = 0; m < 4; m++)
#pragma unroll
                for (int n = 0; n < 4; n++)
                    acc[m][n] = __builtin_amdgcn_mfma_f32_16x16x32_bf16(af[m][kk], w1cur[n][kk], acc[m][n], 0, 0, 0);
        if (s + 1 < S) {
            *(v8s*)&lA[(s + 1) & 1][ar * LAW + ak]     = a0;
            *(v8s*)&lA[(s + 1) & 1][ar * LAW + ak + 8] = a1v;
#pragma unroll
            for (int n = 0; n < 4; n++)
#pragma unroll
                for (int kk = 0; kk < 2; kk++)
                    w1cur[n][kk] = w1nxt[n][kk];
        }
    }

    // ---- stage-1 epilogue: bias + relu -> mT (bf16) ----
#pragma unroll
    for (int n = 0; n < 4; n++) {
        const int gc = wv * 64 + n * 16 + l15;
        const float bv = b1[gc];
#pragma unroll
        for (int m = 0; m < 4; m++)
#pragma unroll
            for (int r = 0; r < 4; r++)
                mT[(m * 16 + kq * 4 + r) * MTW + gc] = f2b(fmaxf(acc[m][n][r] + bv, 0.f));
    }
    __syncthreads();  // mT ready

    if constexpr (!HEAD) {
        // ---- stage 2: C = relu(m @ W2 + b2), barrier-free MFMA ----
#pragma unroll
        for (int m = 0; m < 4; m++)
#pragma unroll
            for (int n = 0; n < 4; n++) acc[m][n] = (v4f){0.f, 0.f, 0.f, 0.f};
#pragma unroll
        for (int kh = 0; kh < 2; kh++) {
            v8s w2r[4][4];
#pragma unroll
            for (int n = 0; n < 4; n++)
#pragma unroll
                for (int kk = 0; kk < 4; kk++)
                    w2r[n][kk] = *(const v8s*)(W2p + (size_t)(kh * 64 + wv * 16 + n * 4 + kk) * 512 + lane * 8);
#pragma unroll
            for (int kk = 0; kk < 4; kk++) {
                v8s a2[4];
#pragma unroll
                for (int m = 0; m < 4; m++)
                    a2[m] = *(const v8s*)&mT[(m * 16 + l15) * MTW + kh * 128 + kk * 32 + kq * 8];
#pragma unroll
                for (int m = 0; m < 4; m++)
#pragma unroll
                    for (int n = 0; n < 4; n++)
                        acc[m][n] = __builtin_amdgcn_mfma_f32_16x16x32_bf16(a2[m], w2r[n][kk], acc[m][n], 0, 0, 0);
            }
        }
        __syncthreads();  // all mT reads done before overwrite
        // write result back into mT (bias+relu+bf16)
#pragma unroll
        for (int n = 0; n < 4; n++) {
            const int gc = wv * 64 + n * 16 + l15;
            const float bv = b2[gc];
#pragma unroll
            for (int m = 0; m < 4; m++)
#pragma unroll
                for (int r = 0; r < 4; r++)
                    mT[(m * 16 + kq * 4 + r) * MTW + gc] = f2b(fmaxf(acc[m][n][r] + bv, 0.f));
        }
        __syncthreads();
        // coalesced blit: thread t -> 16B at row i*8+(t>>5), col (t&31)*8
        ushort* C = (ushort*)outp;
        const int brow = tid >> 5, bcol = (tid & 31) * 8;
#pragma unroll
        for (int i = 0; i < 8; i++) {
            const int row = i * 8 + brow;
            if (row0 + row < M) {
                const v8s v = *(const v8s*)&mT[row * MTW + bcol];
                *(v8s*)&C[(size_t)(row0 + row) * 256 + bcol] = v;
            }
        }
    } else {
        // ---- stage 2 head: o = m @ W2b + b2 (16 cols), log_softmax, fp32 out ----
        v4f h = (v4f){0.f, 0.f, 0.f, 0.f};
        v8s w2r[8];
#pragma unroll
        for (int k8 = 0; k8 < 8; k8++)
            w2r[k8] = *(const v8s*)(W2p + (size_t)k8 * 512 + lane * 8);
#pragma unroll
        for (int k8 = 0; k8 < 8; k8++) {
            const v8s a2 = *(const v8s*)&mT[(wv * 16 + l15) * MTW + k8 * 32 + kq * 8];
            h = __builtin_amdgcn_mfma_f32_16x16x32_bf16(a2, w2r[k8], h, 0, 0, 0);
        }
        float* O = (float*)outp;
        const float bv = b2[l15];
#pragma unroll
        for (int r = 0; r < 4; r++) {
            const float v = h[r] + bv;
            float mx = v;
#pragma unroll
            for (int o = 8; o; o >>= 1) mx = fmaxf(mx, __shfl_xor(mx, o, 16));
            const float e = expf(v - mx);
            float sl = e;
#pragma unroll
            for (int o = 8; o; o >>= 1) sl += __shfl_xor(sl, o, 16);
            const int grow = row0 + wv * 16 + kq * 4 + r;
            if (grow < M) O[(size_t)grow * 16 + l15] = (v - mx) - logf(sl);
        }
    }
}

extern "C" void kernel_launch(void* const* d_in, const int* in_sizes, int n_in,
                              void* d_out, int out_size, void* d_ws, size_t ws_size,
                              hipStream_t stream) {
    (void)in_sizes; (void)n_in; (void)out_size; (void)ws_size;
    const float* x   = (const float*)d_in[0];
    const void*  ei  = d_in[1];
    const float* w1a = (const float*)d_in[2];
    const float* b1a = (const float*)d_in[3];
    const float* w2a = (const float*)d_in[4];
    const float* b2a = (const float*)d_in[5];
    const float* w1b = (const float*)d_in[6];
    const float* b1b = (const float*)d_in[7];
    const float* w2b = (const float*)d_in[8];
    const float* b2b = (const float*)d_in[9];
    float* out = (float*)d_out;

    // ws layout (ushort region first, then ints)
    ushort* XB   = (ushort*)d_ws;                 // [NN][128] bf16: x
    ushort* Z1   = XB + (size_t)NN * 128;         // [NN][128] bf16: z1
    ushort* H1   = Z1 + (size_t)NN * 128;         // [NN][256] bf16: h1
    ushort* Z2   = H1 + (size_t)NN * 256;         // [NN][256] bf16: z2
    ushort* W1pa = Z2 + (size_t)NN * 256;         // 128*256 packed
    ushort* W2pa = W1pa + 128 * 256;              // 256*256 packed
    ushort* W1pb = W2pa + 256 * 256;              // 256*256 packed
    ushort* W2hp = W1pb + 256 * 256;              // 16*256 packed
    int* flag    = (int*)(W2hp + 16 * 256);
    int* deg     = flag + 1;                      // NN
    int* rowptr  = deg + NN;                      // NN+1
    int* cursor  = rowptr + NN + 1;               // NN
    int* csr_src = cursor + NN;                   // NE
    int* bsum    = csr_src + NE;                  // SCAN_BLOCKS
    int* boff    = bsum + SCAN_BLOCKS;            // 256

    // ---- CSR build directly from raw edge index ----
    detect_idx_kernel<<<1, 256, 0, stream>>>((const int*)ei, flag);
    hipMemsetAsync(deg, 0, NN * sizeof(int), stream);
    count_deg_raw_kernel<<<(NE + 255) / 256, 256, 0, stream>>>(ei, flag, deg);
    block_sum_kernel<<<SCAN_BLOCKS, 256, 0, stream>>>(deg, bsum);
    scan_sums_kernel<<<1, 256, 0, stream>>>(bsum, boff, rowptr);
    block_scan_kernel<<<SCAN_BLOCKS, 256, 0, stream>>>(deg, boff, rowptr, cursor);
    fill_csr_raw_kernel<<<(NE + 255) / 256, 256, 0, stream>>>(ei, flag, cursor, csr_src);

    // ---- merged prep: x cvt + all weight packs ----
    prep_kernel<<<XCVT + 656, 256, 0, stream>>>(x, XB, w1a, w2a, w1b, w2b,
                                                W1pa, W2pa, W1pb, W2hp);

    const int aggBlocks = (NN + 3) / 4;
    const int mlpBlocks = (NN + 63) / 64;

    // ---- conv1: aggregate + fused MLP (z1 -> h1) ----
    aggregate_bf16_kernel<128><<<aggBlocks, 256, 0, stream>>>(XB, Z1, rowptr, csr_src);
    fused_mlp_kernel<128, false><<<mlpBlocks, 256, 0, stream>>>(Z1, W1pa, b1a, W2pa, b2a, H1, NN);

    // ---- conv2: aggregate + fused MLP + head (z2 -> out) ----
    aggregate_bf16_kernel<256><<<aggBlocks, 256, 0, stream>>>(H1, Z2, rowptr, csr_src);
    fused_mlp_kernel<256, true><<<mlpBlocks, 256, 0, stream>>>(Z2, W1pb, b1b, W2hp, b2b, out, NN);
}

// Round 16
// 183.553 us; speedup vs baseline: 1.3627x; 1.0461x over previous
//
#include <hip/hip_runtime.h>

#define NN 50000
#define NE 600000
#define SCAN_BLOCKS 196  // 196*256 = 50176 >= NN

typedef short v8s __attribute__((ext_vector_type(8)));
typedef float v4f __attribute__((ext_vector_type(4)));

#define LAW 72    // lA row stride in shorts: 64 data + 8 pad
#define MTW 264   // mT row stride in shorts: 256 data + 8 pad

__device__ __forceinline__ float uaf(unsigned u) {
    union { unsigned u; float f; } v; v.u = u; return v.f;
}
__device__ __forceinline__ ushort f2b(float f) {
    union { float f; unsigned u; } v; v.f = f;
    unsigned r = v.u + 0x7FFFu + ((v.u >> 16) & 1u);  // RNE
    return (ushort)(r >> 16);
}

// ---------- init: zero deg (blocks 0..195) + edge-dtype detect (block 196) ----------
__global__ __launch_bounds__(256) void init_kernel(const int* __restrict__ raw,
                                                    int* __restrict__ flag,
                                                    int* __restrict__ deg) {
    if (blockIdx.x < SCAN_BLOCKS) {
        const int i = blockIdx.x * 256 + threadIdx.x;
        if (i < NN) deg[i] = 0;
    } else {
        __shared__ int cnt;
        if (threadIdx.x == 0) cnt = 0;
        __syncthreads();
        int c = 0;
        for (int i = threadIdx.x; i < 2048; i += 256)
            if (raw[2 * i + 1] != 0) c++;
        atomicAdd(&cnt, c);
        __syncthreads();
        if (threadIdx.x == 0) *flag = (cnt > 10) ? 1 : 0;  // 1 => int32 layout
    }
}

// ---------- merged: degree count (2 edges/thread) + x cvt + weight packing ----------
#define CNTB 1172                  // ceil(NE/2/256)
#define XCVT (NN * 128 / 4 / 256)  // 6250
__device__ __forceinline__ void pack_w1_elem(const float* in, ushort* out, int o) {
    int j = o & 7, lane = (o >> 3) & 63, f = o >> 9;
    int kk = f & 1, n = (f >> 1) & 3, wv = (f >> 3) & 3, s = f >> 5;
    int k = s * 64 + kk * 32 + (lane >> 4) * 8 + j;
    int col = wv * 64 + n * 16 + (lane & 15);
    out[o] = f2b(in[(size_t)k * 256 + col]);
}
__global__ __launch_bounds__(256) void count_prep_kernel(const void* __restrict__ raw,
                                                          const int* __restrict__ flag,
                                                          int* __restrict__ deg,
                                                          const float* __restrict__ x,
                                                          ushort* __restrict__ XB,
                                                          const float* __restrict__ w1a,
                                                          const float* __restrict__ w2a,
                                                          const float* __restrict__ w1b,
                                                          const float* __restrict__ wh,
                                                          ushort* __restrict__ W1pa,
                                                          ushort* __restrict__ W2pa,
                                                          ushort* __restrict__ W1pb,
                                                          ushort* __restrict__ W2hp) {
    const int b = blockIdx.x;
    if (b < CNTB) {
        const int e2 = b * 256 + threadIdx.x;      // handles edges 2*e2, 2*e2+1
        const int e = e2 * 2;
        if (e >= NE) return;
        int d0, d1;
        if (*flag) {
            const int2 d = *(const int2*)&((const int*)raw)[NE + e];
            d0 = d.x; d1 = d.y;
        } else {
            const longlong2 d = *(const longlong2*)&((const long long*)raw)[NE + e];
            d0 = (int)d.x; d1 = (int)d.y;
        }
        atomicAdd(&deg[d0], 1);
        if (e + 1 < NE) atomicAdd(&deg[d1], 1);
    } else if (b < CNTB + XCVT) {
        const int i = (b - CNTB) * 256 + threadIdx.x;
        const float4 v = *(const float4*)&x[(size_t)i * 4];
        ushort4 o;
        o.x = f2b(v.x); o.y = f2b(v.y); o.z = f2b(v.z); o.w = f2b(v.w);
        *(ushort4*)&XB[(size_t)i * 4] = o;
    } else if (b < CNTB + XCVT + 128) {
        pack_w1_elem(w1a, W1pa, (b - CNTB - XCVT) * 256 + threadIdx.x);
    } else if (b < CNTB + XCVT + 384) {
        int o = (b - CNTB - XCVT - 128) * 256 + threadIdx.x;
        int j = o & 7, lane = (o >> 3) & 63, f = o >> 9;
        int kk = f & 3, n = (f >> 2) & 3, wv = (f >> 4) & 3, kh = f >> 6;
        int k = kh * 128 + kk * 32 + (lane >> 4) * 8 + j;
        int col = wv * 64 + n * 16 + (lane & 15);
        W2pa[o] = f2b(w2a[(size_t)k * 256 + col]);
    } else if (b < CNTB + XCVT + 640) {
        pack_w1_elem(w1b, W1pb, (b - CNTB - XCVT - 384) * 256 + threadIdx.x);
    } else {
        int o = (b - CNTB - XCVT - 640) * 256 + threadIdx.x;
        int j = o & 7, lane = (o >> 3) & 63, k8 = o >> 9;
        int k = k8 * 32 + (lane >> 4) * 8 + j;
        int col = lane & 15;
        W2hp[o] = f2b(wh[(size_t)k * 16 + col]);
    }
}

// ---------- hierarchical scan: deg[NN] -> rowptr[NN+1], cursor[NN] ----------
__global__ __launch_bounds__(256) void block_sum_kernel(const int* __restrict__ deg,
                                                         int* __restrict__ bsum) {
    const int i = blockIdx.x * 256 + threadIdx.x;
    int v = (i < NN) ? deg[i] : 0;
#pragma unroll
    for (int o = 32; o; o >>= 1) v += __shfl_down(v, o, 64);
    __shared__ int ws[4];
    if ((threadIdx.x & 63) == 0) ws[threadIdx.x >> 6] = v;
    __syncthreads();
    if (threadIdx.x == 0) bsum[blockIdx.x] = ws[0] + ws[1] + ws[2] + ws[3];
}

__global__ __launch_bounds__(256) void scan_sums_kernel(const int* __restrict__ bsum,
                                                         int* __restrict__ boff,
                                                         int* __restrict__ rowptr) {
    __shared__ int tmp[256];
    const int t = threadIdx.x;
    const int v = (t < SCAN_BLOCKS) ? bsum[t] : 0;
    tmp[t] = v;
    __syncthreads();
#pragma unroll
    for (int off = 1; off < 256; off <<= 1) {
        int u = (t >= off) ? tmp[t - off] : 0;
        __syncthreads();
        tmp[t] += u;
        __syncthreads();
    }
    boff[t] = tmp[t] - v;  // exclusive
    if (t == 255) rowptr[NN] = tmp[255];
}

__global__ __launch_bounds__(256) void block_scan_kernel(const int* __restrict__ deg,
                                                          const int* __restrict__ boff,
                                                          int* __restrict__ rowptr,
                                                          int* __restrict__ cursor) {
    const int t = threadIdx.x;
    const int i = blockIdx.x * 256 + t;
    const int lane = t & 63, w = t >> 6;
    const int v = (i < NN) ? deg[i] : 0;
    int s = v;
#pragma unroll
    for (int o = 1; o < 64; o <<= 1) {
        int u = __shfl_up(s, o, 64);
        if (lane >= o) s += u;
    }
    __shared__ int wsum[4];
    if (lane == 63) wsum[w] = s;
    __syncthreads();
    int wpre = 0;
    for (int k = 0; k < w; k++) wpre += wsum[k];
    const int excl = boff[blockIdx.x] + wpre + s - v;
    if (i < NN) {
        rowptr[i] = excl;
        cursor[i] = excl;
    }
}

// CSR fill from raw edges, 2 edges/thread
__global__ __launch_bounds__(256) void fill_csr_raw_kernel(const void* __restrict__ raw,
                                                            const int* __restrict__ flag,
                                                            int* __restrict__ cursor,
                                                            int* __restrict__ csr_src) {
    const int e2 = blockIdx.x * 256 + threadIdx.x;
    const int e = e2 * 2;
    if (e >= NE) return;
    int s0, s1, d0, d1;
    if (*flag) {
        const int2 s = *(const int2*)&((const int*)raw)[e];
        const int2 d = *(const int2*)&((const int*)raw)[NE + e];
        s0 = s.x; s1 = s.y; d0 = d.x; d1 = d.y;
    } else {
        const longlong2 s = *(const longlong2*)&((const long long*)raw)[e];
        const longlong2 d = *(const longlong2*)&((const long long*)raw)[NE + e];
        s0 = (int)s.x; s1 = (int)s.y; d0 = (int)d.x; d1 = (int)d.y;
    }
    int pos = atomicAdd(&cursor[d0], 1);
    csr_src[pos] = s0;
    if (e + 1 < NE) {
        pos = atomicAdd(&cursor[d1], 1);
        csr_src[pos] = s1;
    }
}

// ---------- gather-aggregate v2: scalar index path, 8 gathers in flight ----------
template <int D>
__global__ __launch_bounds__(256) void aggregate_bf16_kernel(const ushort* __restrict__ feat,
                                                              ushort* __restrict__ z,
                                                              const int* __restrict__ rowptr,
                                                              const int* __restrict__ csr_src) {
    const int node = __builtin_amdgcn_readfirstlane(blockIdx.x * 4 + (threadIdx.x >> 6));
    const int lane = threadIdx.x & 63;
    if (node >= NN) return;
    const int rbeg = rowptr[node];
    const int rend = rowptr[node + 1];

    if constexpr (D == 256) {
        const size_t base = (size_t)node * 256 + lane * 4;
        const uint2 sv = *(const uint2*)&feat[base];
        float a0 = uaf(sv.x << 16), a1 = uaf(sv.x & 0xFFFF0000u);
        float a2 = uaf(sv.y << 16), a3 = uaf(sv.y & 0xFFFF0000u);
        int j = rbeg;
        for (; j + 7 < rend; j += 8) {
            uint2 v[8];
#pragma unroll
            for (int q = 0; q < 8; q++)
                v[q] = *(const uint2*)&feat[(size_t)csr_src[j + q] * 256 + lane * 4];
#pragma unroll
            for (int q = 0; q < 8; q++) {
                a0 += uaf(v[q].x << 16); a1 += uaf(v[q].x & 0xFFFF0000u);
                a2 += uaf(v[q].y << 16); a3 += uaf(v[q].y & 0xFFFF0000u);
            }
        }
        for (; j + 3 < rend; j += 4) {
            uint2 v[4];
#pragma unroll
            for (int q = 0; q < 4; q++)
                v[q] = *(const uint2*)&feat[(size_t)csr_src[j + q] * 256 + lane * 4];
#pragma unroll
            for (int q = 0; q < 4; q++) {
                a0 += uaf(v[q].x << 16); a1 += uaf(v[q].x & 0xFFFF0000u);
                a2 += uaf(v[q].y << 16); a3 += uaf(v[q].y & 0xFFFF0000u);
            }
        }
        for (; j < rend; j++) {
            const uint2 v = *(const uint2*)&feat[(size_t)csr_src[j] * 256 + lane * 4];
            a0 += uaf(v.x << 16); a1 += uaf(v.x & 0xFFFF0000u);
            a2 += uaf(v.y << 16); a3 += uaf(v.y & 0xFFFF0000u);
        }
        uint2 o;
        o.x = (uint)f2b(a0) | ((uint)f2b(a1) << 16);
        o.y = (uint)f2b(a2) | ((uint)f2b(a3) << 16);
        *(uint2*)&z[base] = o;
    } else {  // D == 128
        const size_t base = (size_t)node * 128 + lane * 2;
        const uint sv = *(const uint*)&feat[base];
        float a0 = uaf(sv << 16), a1 = uaf(sv & 0xFFFF0000u);
        int j = rbeg;
        for (; j + 7 < rend; j += 8) {
            uint v[8];
#pragma unroll
            for (int q = 0; q < 8; q++)
                v[q] = *(const uint*)&feat[(size_t)csr_src[j + q] * 128 + lane * 2];
#pragma unroll
            for (int q = 0; q < 8; q++) {
                a0 += uaf(v[q] << 16); a1 += uaf(v[q] & 0xFFFF0000u);
            }
        }
        for (; j + 3 < rend; j += 4) {
            uint v[4];
#pragma unroll
            for (int q = 0; q < 4; q++)
                v[q] = *(const uint*)&feat[(size_t)csr_src[j + q] * 128 + lane * 2];
#pragma unroll
            for (int q = 0; q < 4; q++) {
                a0 += uaf(v[q] << 16); a1 += uaf(v[q] & 0xFFFF0000u);
            }
        }
        for (; j < rend; j++) {
            const uint v = *(const uint*)&feat[(size_t)csr_src[j] * 128 + lane * 2];
            a0 += uaf(v << 16); a1 += uaf(v & 0xFFFF0000u);
        }
        *(uint*)&z[base] = (uint)f2b(a0) | ((uint)f2b(a1) << 16);
    }
}

// ---------- fused 2-layer MLP v5: frag-major W + blit epilogue (round-12/13) ----------
template <int K1, bool HEAD>
__global__ __launch_bounds__(256) void fused_mlp_kernel(const ushort* __restrict__ A,
                                                         const ushort* __restrict__ W1p,
                                                         const float* __restrict__ b1,
                                                         const ushort* __restrict__ W2p,
                                                         const float* __restrict__ b2,
                                                         void* __restrict__ outp, int M) {
    constexpr int S = K1 / 64;          // stage-1 k-steps
    __shared__ ushort lA[2][64 * LAW];  // 18.4 KB dbuf A k-tile [64][64]
    __shared__ ushort mT[64 * MTW];     // 33.8 KB stage-1 output [64][256] bf16
    const int tid = threadIdx.x;
    const int lane = tid & 63;
    const int wv = tid >> 6;
    const int row0 = blockIdx.x * 64;
    const int l15 = lane & 15;
    const int kq = lane >> 4;
    const int ar = tid >> 2, ak = (tid & 3) * 16;  // A staging: row, k-chunk

    const bool aok = (row0 + ar) < M;
    const ushort* Arow = A + (size_t)(row0 + ar) * K1 + ak;

    v4f acc[4][4];
#pragma unroll
    for (int m = 0; m < 4; m++)
#pragma unroll
        for (int n = 0; n < 4; n++) acc[m][n] = (v4f){0.f, 0.f, 0.f, 0.f};

    v8s a0 = {}, a1v = {};
    v8s w1cur[4][2], w1nxt[4][2];

    // ---- prologue: step-0 A + W1 (contiguous frag loads) ----
    if (aok) { a0 = *(const v8s*)Arow; a1v = *(const v8s*)(Arow + 8); }
#pragma unroll
    for (int n = 0; n < 4; n++)
#pragma unroll
        for (int kk = 0; kk < 2; kk++)
            w1cur[n][kk] = *(const v8s*)(W1p + (size_t)(wv * 8 + n * 2 + kk) * 512 + lane * 8);
    *(v8s*)&lA[0][ar * LAW + ak]     = a0;
    *(v8s*)&lA[0][ar * LAW + ak + 8] = a1v;

    // ---- stage 1: m = relu(A @ W1 + b1) ----
#pragma unroll
    for (int s = 0; s < S; s++) {
        __syncthreads();
        if (s + 1 < S) {
            a0 = (v8s){}; a1v = (v8s){};
            if (aok) {
                a0  = *(const v8s*)(Arow + (s + 1) * 64);
                a1v = *(const v8s*)(Arow + (s + 1) * 64 + 8);
            }
#pragma unroll
            for (int n = 0; n < 4; n++)
#pragma unroll
                for (int kk = 0; kk < 2; kk++)
                    w1nxt[n][kk] = *(const v8s*)(W1p + (size_t)((s + 1) * 32 + wv * 8 + n * 2 + kk) * 512 + lane * 8);
        }
        v8s af[4][2];
#pragma unroll
        for (int m = 0; m < 4; m++)
#pragma unroll
            for (int kk = 0; kk < 2; kk++)
                af[m][kk] = *(const v8s*)&lA[s & 1][(m * 16 + l15) * LAW + kk * 32 + kq * 8];
#pragma unroll
        for (int kk = 0; kk < 2; kk++)
#pragma unroll
            for (int m = 0; m < 4; m++)
#pragma unroll
                for (int n = 0; n < 4; n++)
                    acc[m][n] = __builtin_amdgcn_mfma_f32_16x16x32_bf16(af[m][kk], w1cur[n][kk], acc[m][n], 0, 0, 0);
        if (s + 1 < S) {
            *(v8s*)&lA[(s + 1) & 1][ar * LAW + ak]     = a0;
            *(v8s*)&lA[(s + 1) & 1][ar * LAW + ak + 8] = a1v;
#pragma unroll
            for (int n = 0; n < 4; n++)
#pragma unroll
                for (int kk = 0; kk < 2; kk++)
                    w1cur[n][kk] = w1nxt[n][kk];
        }
    }

    // ---- stage-1 epilogue: bias + relu -> mT (bf16) ----
#pragma unroll
    for (int n = 0; n < 4; n++) {
        const int gc = wv * 64 + n * 16 + l15;
        const float bv = b1[gc];
#pragma unroll
        for (int m = 0; m < 4; m++)
#pragma unroll
            for (int r = 0; r < 4; r++)
                mT[(m * 16 + kq * 4 + r) * MTW + gc] = f2b(fmaxf(acc[m][n][r] + bv, 0.f));
    }
    __syncthreads();  // mT ready

    if constexpr (!HEAD) {
        // ---- stage 2: C = relu(m @ W2 + b2), barrier-free MFMA ----
#pragma unroll
        for (int m = 0; m < 4; m++)
#pragma unroll
            for (int n = 0; n < 4; n++) acc[m][n] = (v4f){0.f, 0.f, 0.f, 0.f};
#pragma unroll
        for (int kh = 0; kh < 2; kh++) {
            v8s w2r[4][4];
#pragma unroll
            for (int n = 0; n < 4; n++)
#pragma unroll
                for (int kk = 0; kk < 4; kk++)
                    w2r[n][kk] = *(const v8s*)(W2p + (size_t)(kh * 64 + wv * 16 + n * 4 + kk) * 512 + lane * 8);
#pragma unroll
            for (int kk = 0; kk < 4; kk++) {
                v8s a2[4];
#pragma unroll
                for (int m = 0; m < 4; m++)
                    a2[m] = *(const v8s*)&mT[(m * 16 + l15) * MTW + kh * 128 + kk * 32 + kq * 8];
#pragma unroll
                for (int m = 0; m < 4; m++)
#pragma unroll
                    for (int n = 0; n < 4; n++)
                        acc[m][n] = __builtin_amdgcn_mfma_f32_16x16x32_bf16(a2[m], w2r[n][kk], acc[m][n], 0, 0, 0);
            }
        }
        __syncthreads();  // all mT reads done before overwrite
        // write result back into mT (bias+relu+bf16)
#pragma unroll
        for (int n = 0; n < 4; n++) {
            const int gc = wv * 64 + n * 16 + l15;
            const float bv = b2[gc];
#pragma unroll
            for (int m = 0; m < 4; m++)
#pragma unroll
                for (int r = 0; r < 4; r++)
                    mT[(m * 16 + kq * 4 + r) * MTW + gc] = f2b(fmaxf(acc[m][n][r] + bv, 0.f));
        }
        __syncthreads();
        // coalesced blit: thread t -> 16B at row i*8+(t>>5), col (t&31)*8
        ushort* C = (ushort*)outp;
        const int brow = tid >> 5, bcol = (tid & 31) * 8;
#pragma unroll
        for (int i = 0; i < 8; i++) {
            const int row = i * 8 + brow;
            if (row0 + row < M) {
                const v8s v = *(const v8s*)&mT[row * MTW + bcol];
                *(v8s*)&C[(size_t)(row0 + row) * 256 + bcol] = v;
            }
        }
    } else {
        // ---- stage 2 head: o = m @ W2b + b2 (16 cols), log_softmax, fp32 out ----
        v4f h = (v4f){0.f, 0.f, 0.f, 0.f};
        v8s w2r[8];
#pragma unroll
        for (int k8 = 0; k8 < 8; k8++)
            w2r[k8] = *(const v8s*)(W2p + (size_t)k8 * 512 + lane * 8);
#pragma unroll
        for (int k8 = 0; k8 < 8; k8++) {
            const v8s a2 = *(const v8s*)&mT[(wv * 16 + l15) * MTW + k8 * 32 + kq * 8];
            h = __builtin_amdgcn_mfma_f32_16x16x32_bf16(a2, w2r[k8], h, 0, 0, 0);
        }
        float* O = (float*)outp;
        const float bv = b2[l15];
#pragma unroll
        for (int r = 0; r < 4; r++) {
            const float v = h[r] + bv;
            float mx = v;
#pragma unroll
            for (int o = 8; o; o >>= 1) mx = fmaxf(mx, __shfl_xor(mx, o, 16));
            const float e = expf(v - mx);
            float sl = e;
#pragma unroll
            for (int o = 8; o; o >>= 1) sl += __shfl_xor(sl, o, 16);
            const int grow = row0 + wv * 16 + kq * 4 + r;
            if (grow < M) O[(size_t)grow * 16 + l15] = (v - mx) - logf(sl);
        }
    }
}

extern "C" void kernel_launch(void* const* d_in, const int* in_sizes, int n_in,
                              void* d_out, int out_size, void* d_ws, size_t ws_size,
                              hipStream_t stream) {
    (void)in_sizes; (void)n_in; (void)out_size; (void)ws_size;
    const float* x   = (const float*)d_in[0];
    const void*  ei  = d_in[1];
    const float* w1a = (const float*)d_in[2];
    const float* b1a = (const float*)d_in[3];
    const float* w2a = (const float*)d_in[4];
    const float* b2a = (const float*)d_in[5];
    const float* w1b = (const float*)d_in[6];
    const float* b1b = (const float*)d_in[7];
    const float* w2b = (const float*)d_in[8];
    const float* b2b = (const float*)d_in[9];
    float* out = (float*)d_out;

    // ws layout (ushort region first, then ints)
    ushort* XB   = (ushort*)d_ws;                 // [NN][128] bf16: x
    ushort* Z1   = XB + (size_t)NN * 128;         // [NN][128] bf16: z1
    ushort* H1   = Z1 + (size_t)NN * 128;         // [NN][256] bf16: h1
    ushort* Z2   = H1 + (size_t)NN * 256;         // [NN][256] bf16: z2
    ushort* W1pa = Z2 + (size_t)NN * 256;         // 128*256 packed
    ushort* W2pa = W1pa + 128 * 256;              // 256*256 packed
    ushort* W1pb = W2pa + 256 * 256;              // 256*256 packed
    ushort* W2hp = W1pb + 256 * 256;              // 16*256 packed
    int* flag    = (int*)(W2hp + 16 * 256);
    int* deg     = flag + 1;                      // NN
    int* rowptr  = deg + NN;                      // NN+1
    int* cursor  = rowptr + NN + 1;               // NN
    int* csr_src = cursor + NN;                   // NE
    int* bsum    = csr_src + NE;                  // SCAN_BLOCKS
    int* boff    = bsum + SCAN_BLOCKS;            // 256

    // ---- init (deg zero + dtype detect), then count+prep merged ----
    init_kernel<<<SCAN_BLOCKS + 1, 256, 0, stream>>>((const int*)ei, flag, deg);
    count_prep_kernel<<<CNTB + XCVT + 656, 256, 0, stream>>>(
        ei, flag, deg, x, XB, w1a, w2a, w1b, w2b, W1pa, W2pa, W1pb, W2hp);

    // ---- CSR scan + fill ----
    block_sum_kernel<<<SCAN_BLOCKS, 256, 0, stream>>>(deg, bsum);
    scan_sums_kernel<<<1, 256, 0, stream>>>(bsum, boff, rowptr);
    block_scan_kernel<<<SCAN_BLOCKS, 256, 0, stream>>>(deg, boff, rowptr, cursor);
    fill_csr_raw_kernel<<<CNTB, 256, 0, stream>>>(ei, flag, cursor, csr_src);

    const int aggBlocks = (NN + 3) / 4;
    const int mlpBlocks = (NN + 63) / 64;

    // ---- conv1: aggregate + fused MLP (z1 -> h1) ----
    aggregate_bf16_kernel<128><<<aggBlocks, 256, 0, stream>>>(XB, Z1, rowptr, csr_src);
    fused_mlp_kernel<128, false><<<mlpBlocks, 256, 0, stream>>>(Z1, W1pa, b1a, W2pa, b2a, H1, NN);

    // ---- conv2: aggregate + fused MLP + head (z2 -> out) ----
    aggregate_bf16_kernel<256><<<aggBlocks, 256, 0, stream>>>(H1, Z2, rowptr, csr_src);
    fused_mlp_kernel<256, true><<<mlpBlocks, 256, 0, stream>>>(Z2, W1pb, b1b, W2hp, b2b, out, NN);
}

// Round 17
// 183.437 us; speedup vs baseline: 1.3636x; 1.0006x over previous
//
#include <hip/hip_runtime.h>

#define NN 50000
#define NE 600000
#define SCAN_BLOCKS 196  // 196*256 = 50176 >= NN

typedef short v8s __attribute__((ext_vector_type(8)));
typedef float v4f __attribute__((ext_vector_type(4)));

#define LAW 72    // lA row stride in shorts: 64 data + 8 pad
#define MTW 264   // mT row stride in shorts: 256 data + 8 pad

__device__ __forceinline__ float uaf(unsigned u) {
    union { unsigned u; float f; } v; v.u = u; return v.f;
}
__device__ __forceinline__ ushort f2b(float f) {
    union { float f; unsigned u; } v; v.f = f;
    unsigned r = v.u + 0x7FFFu + ((v.u >> 16) & 1u);  // RNE
    return (ushort)(r >> 16);
}

// ---------- init: zero deg (blocks 0..195) + edge-dtype detect (block 196) ----------
__global__ __launch_bounds__(256) void init_kernel(const int* __restrict__ raw,
                                                    int* __restrict__ flag,
                                                    int* __restrict__ deg) {
    if (blockIdx.x < SCAN_BLOCKS) {
        const int i = blockIdx.x * 256 + threadIdx.x;
        if (i < NN) deg[i] = 0;
    } else {
        __shared__ int cnt;
        if (threadIdx.x == 0) cnt = 0;
        __syncthreads();
        int c = 0;
        for (int i = threadIdx.x; i < 2048; i += 256)
            if (raw[2 * i + 1] != 0) c++;
        atomicAdd(&cnt, c);
        __syncthreads();
        if (threadIdx.x == 0) *flag = (cnt > 10) ? 1 : 0;  // 1 => int32 layout
    }
}

// ---------- merged: degree count (2 edges/thread) + x cvt + weight packing ----------
#define CNTB 1172                  // ceil(NE/2/256)
#define XCVT (NN * 128 / 4 / 256)  // 6250
__device__ __forceinline__ void pack_w1_elem(const float* in, ushort* out, int o) {
    int j = o & 7, lane = (o >> 3) & 63, f = o >> 9;
    int kk = f & 1, n = (f >> 1) & 3, wv = (f >> 3) & 3, s = f >> 5;
    int k = s * 64 + kk * 32 + (lane >> 4) * 8 + j;
    int col = wv * 64 + n * 16 + (lane & 15);
    out[o] = f2b(in[(size_t)k * 256 + col]);
}
__global__ __launch_bounds__(256) void count_prep_kernel(const void* __restrict__ raw,
                                                          const int* __restrict__ flag,
                                                          int* __restrict__ deg,
                                                          const float* __restrict__ x,
                                                          ushort* __restrict__ XB,
                                                          const float* __restrict__ w1a,
                                                          const float* __restrict__ w2a,
                                                          const float* __restrict__ w1b,
                                                          const float* __restrict__ wh,
                                                          ushort* __restrict__ W1pa,
                                                          ushort* __restrict__ W2pa,
                                                          ushort* __restrict__ W1pb,
                                                          ushort* __restrict__ W2hp) {
    const int b = blockIdx.x;
    if (b < CNTB) {
        const int e2 = b * 256 + threadIdx.x;      // handles edges 2*e2, 2*e2+1
        const int e = e2 * 2;
        if (e >= NE) return;
        int d0, d1;
        if (*flag) {
            const int2 d = *(const int2*)&((const int*)raw)[NE + e];
            d0 = d.x; d1 = d.y;
        } else {
            const longlong2 d = *(const longlong2*)&((const long long*)raw)[NE + e];
            d0 = (int)d.x; d1 = (int)d.y;
        }
        atomicAdd(&deg[d0], 1);
        if (e + 1 < NE) atomicAdd(&deg[d1], 1);
    } else if (b < CNTB + XCVT) {
        const int i = (b - CNTB) * 256 + threadIdx.x;
        const float4 v = *(const float4*)&x[(size_t)i * 4];
        ushort4 o;
        o.x = f2b(v.x); o.y = f2b(v.y); o.z = f2b(v.z); o.w = f2b(v.w);
        *(ushort4*)&XB[(size_t)i * 4] = o;
    } else if (b < CNTB + XCVT + 128) {
        pack_w1_elem(w1a, W1pa, (b - CNTB - XCVT) * 256 + threadIdx.x);
    } else if (b < CNTB + XCVT + 384) {
        int o = (b - CNTB - XCVT - 128) * 256 + threadIdx.x;
        int j = o & 7, lane = (o >> 3) & 63, f = o >> 9;
        int kk = f & 3, n = (f >> 2) & 3, wv = (f >> 4) & 3, kh = f >> 6;
        int k = kh * 128 + kk * 32 + (lane >> 4) * 8 + j;
        int col = wv * 64 + n * 16 + (lane & 15);
        W2pa[o] = f2b(w2a[(size_t)k * 256 + col]);
    } else if (b < CNTB + XCVT + 640) {
        pack_w1_elem(w1b, W1pb, (b - CNTB - XCVT - 384) * 256 + threadIdx.x);
    } else {
        int o = (b - CNTB - XCVT - 640) * 256 + threadIdx.x;
        int j = o & 7, lane = (o >> 3) & 63, k8 = o >> 9;
        int k = k8 * 32 + (lane >> 4) * 8 + j;
        int col = lane & 15;
        W2hp[o] = f2b(wh[(size_t)k * 16 + col]);
    }
}

// ---------- hierarchical scan: deg[NN] -> rowptr[NN+1], cursor[NN] ----------
__global__ __launch_bounds__(256) void block_sum_kernel(const int* __restrict__ deg,
                                                         int* __restrict__ bsum) {
    const int i = blockIdx.x * 256 + threadIdx.x;
    int v = (i < NN) ? deg[i] : 0;
#pragma unroll
    for (int o = 32; o; o >>= 1) v += __shfl_down(v, o, 64);
    __shared__ int ws[4];
    if ((threadIdx.x & 63) == 0) ws[threadIdx.x >> 6] = v;
    __syncthreads();
    if (threadIdx.x == 0) bsum[blockIdx.x] = ws[0] + ws[1] + ws[2] + ws[3];
}

__global__ __launch_bounds__(256) void scan_sums_kernel(const int* __restrict__ bsum,
                                                         int* __restrict__ boff,
                                                         int* __restrict__ rowptr) {
    __shared__ int tmp[256];
    const int t = threadIdx.x;
    const int v = (t < SCAN_BLOCKS) ? bsum[t] : 0;
    tmp[t] = v;
    __syncthreads();
#pragma unroll
    for (int off = 1; off < 256; off <<= 1) {
        int u = (t >= off) ? tmp[t - off] : 0;
        __syncthreads();
        tmp[t] += u;
        __syncthreads();
    }
    boff[t] = tmp[t] - v;  // exclusive
    if (t == 255) rowptr[NN] = tmp[255];
}

__global__ __launch_bounds__(256) void block_scan_kernel(const int* __restrict__ deg,
                                                          const int* __restrict__ boff,
                                                          int* __restrict__ rowptr,
                                                          int* __restrict__ cursor) {
    const int t = threadIdx.x;
    const int i = blockIdx.x * 256 + t;
    const int lane = t & 63, w = t >> 6;
    const int v = (i < NN) ? deg[i] : 0;
    int s = v;
#pragma unroll
    for (int o = 1; o < 64; o <<= 1) {
        int u = __shfl_up(s, o, 64);
        if (lane >= o) s += u;
    }
    __shared__ int wsum[4];
    if (lane == 63) wsum[w] = s;
    __syncthreads();
    int wpre = 0;
    for (int k = 0; k < w; k++) wpre += wsum[k];
    const int excl = boff[blockIdx.x] + wpre + s - v;
    if (i < NN) {
        rowptr[i] = excl;
        cursor[i] = excl;
    }
}

// CSR fill from raw edges, 2 edges/thread
__global__ __launch_bounds__(256) void fill_csr_raw_kernel(const void* __restrict__ raw,
                                                            const int* __restrict__ flag,
                                                            int* __restrict__ cursor,
                                                            int* __restrict__ csr_src) {
    const int e2 = blockIdx.x * 256 + threadIdx.x;
    const int e = e2 * 2;
    if (e >= NE) return;
    int s0, s1, d0, d1;
    if (*flag) {
        const int2 s = *(const int2*)&((const int*)raw)[e];
        const int2 d = *(const int2*)&((const int*)raw)[NE + e];
        s0 = s.x; s1 = s.y; d0 = d.x; d1 = d.y;
    } else {
        const longlong2 s = *(const longlong2*)&((const long long*)raw)[e];
        const longlong2 d = *(const longlong2*)&((const long long*)raw)[NE + e];
        s0 = (int)s.x; s1 = (int)s.y; d0 = (int)d.x; d1 = (int)d.y;
    }
    int pos = atomicAdd(&cursor[d0], 1);
    csr_src[pos] = s0;
    if (e + 1 < NE) {
        pos = atomicAdd(&cursor[d1], 1);
        csr_src[pos] = s1;
    }
}

// ---------- gather-aggregate v2: scalar index path, 8 gathers in flight ----------
template <int D>
__global__ __launch_bounds__(256) void aggregate_bf16_kernel(const ushort* __restrict__ feat,
                                                              ushort* __restrict__ z,
                                                              const int* __restrict__ rowptr,
                                                              const int* __restrict__ csr_src) {
    const int node = __builtin_amdgcn_readfirstlane(blockIdx.x * 4 + (threadIdx.x >> 6));
    const int lane = threadIdx.x & 63;
    if (node >= NN) return;
    const int rbeg = rowptr[node];
    const int rend = rowptr[node + 1];

    if constexpr (D == 256) {
        const size_t base = (size_t)node * 256 + lane * 4;
        const uint2 sv = *(const uint2*)&feat[base];
        float a0 = uaf(sv.x << 16), a1 = uaf(sv.x & 0xFFFF0000u);
        float a2 = uaf(sv.y << 16), a3 = uaf(sv.y & 0xFFFF0000u);
        int j = rbeg;
        for (; j + 7 < rend; j += 8) {
            uint2 v[8];
#pragma unroll
            for (int q = 0; q < 8; q++)
                v[q] = *(const uint2*)&feat[(size_t)csr_src[j + q] * 256 + lane * 4];
#pragma unroll
            for (int q = 0; q < 8; q++) {
                a0 += uaf(v[q].x << 16); a1 += uaf(v[q].x & 0xFFFF0000u);
                a2 += uaf(v[q].y << 16); a3 += uaf(v[q].y & 0xFFFF0000u);
            }
        }
        for (; j + 3 < rend; j += 4) {
            uint2 v[4];
#pragma unroll
            for (int q = 0; q < 4; q++)
                v[q] = *(const uint2*)&feat[(size_t)csr_src[j + q] * 256 + lane * 4];
#pragma unroll
            for (int q = 0; q < 4; q++) {
                a0 += uaf(v[q].x << 16); a1 += uaf(v[q].x & 0xFFFF0000u);
                a2 += uaf(v[q].y << 16); a3 += uaf(v[q].y & 0xFFFF0000u);
            }
        }
        for (; j < rend; j++) {
            const uint2 v = *(const uint2*)&feat[(size_t)csr_src[j] * 256 + lane * 4];
            a0 += uaf(v.x << 16); a1 += uaf(v.x & 0xFFFF0000u);
            a2 += uaf(v.y << 16); a3 += uaf(v.y & 0xFFFF0000u);
        }
        uint2 o;
        o.x = (uint)f2b(a0) | ((uint)f2b(a1) << 16);
        o.y = (uint)f2b(a2) | ((uint)f2b(a3) << 16);
        *(uint2*)&z[base] = o;
    } else {  // D == 128
        const size_t base = (size_t)node * 128 + lane * 2;
        const uint sv = *(const uint*)&feat[base];
        float a0 = uaf(sv << 16), a1 = uaf(sv & 0xFFFF0000u);
        int j = rbeg;
        for (; j + 7 < rend; j += 8) {
            uint v[8];
#pragma unroll
            for (int q = 0; q < 8; q++)
                v[q] = *(const uint*)&feat[(size_t)csr_src[j + q] * 128 + lane * 2];
#pragma unroll
            for (int q = 0; q < 8; q++) {
                a0 += uaf(v[q] << 16); a1 += uaf(v[q] & 0xFFFF0000u);
            }
        }
        for (; j + 3 < rend; j += 4) {
            uint v[4];
#pragma unroll
            for (int q = 0; q < 4; q++)
                v[q] = *(const uint*)&feat[(size_t)csr_src[j + q] * 128 + lane * 2];
#pragma unroll
            for (int q = 0; q < 4; q++) {
                a0 += uaf(v[q] << 16); a1 += uaf(v[q] & 0xFFFF0000u);
            }
        }
        for (; j < rend; j++) {
            const uint v = *(const uint*)&feat[(size_t)csr_src[j] * 128 + lane * 2];
            a0 += uaf(v << 16); a1 += uaf(v & 0xFFFF0000u);
        }
        *(uint*)&z[base] = (uint)f2b(a0) | ((uint)f2b(a1) << 16);
    }
}

// ---------- fused 2-layer MLP v5: frag-major W + blit epilogue (round-12/13) ----------
template <int K1, bool HEAD>
__global__ __launch_bounds__(256) void fused_mlp_kernel(const ushort* __restrict__ A,
                                                         const ushort* __restrict__ W1p,
                                                         const float* __restrict__ b1,
                                                         const ushort* __restrict__ W2p,
                                                         const float* __restrict__ b2,
                                                         void* __restrict__ outp, int M) {
    constexpr int S = K1 / 64;          // stage-1 k-steps
    __shared__ ushort lA[2][64 * LAW];  // 18.4 KB dbuf A k-tile [64][64]
    __shared__ ushort mT[64 * MTW];     // 33.8 KB stage-1 output [64][256] bf16
    const int tid = threadIdx.x;
    const int lane = tid & 63;
    const int wv = tid >> 6;
    const int row0 = blockIdx.x * 64;
    const int l15 = lane & 15;
    const int kq = lane >> 4;
    const int ar = tid >> 2, ak = (tid & 3) * 16;  // A staging: row, k-chunk

    const bool aok = (row0 + ar) < M;
    const ushort* Arow = A + (size_t)(row0 + ar) * K1 + ak;

    v4f acc[4][4];
#pragma unroll
    for (int m = 0; m < 4; m++)
#pragma unroll
        for (int n = 0; n < 4; n++) acc[m][n] = (v4f){0.f, 0.f, 0.f, 0.f};

    v8s a0 = {}, a1v = {};
    v8s w1cur[4][2], w1nxt[4][2];

    // ---- prologue: step-0 A + W1 (contiguous frag loads) ----
    if (aok) { a0 = *(const v8s*)Arow; a1v = *(const v8s*)(Arow + 8); }
#pragma unroll
    for (int n = 0; n < 4; n++)
#pragma unroll
        for (int kk = 0; kk < 2; kk++)
            w1cur[n][kk] = *(const v8s*)(W1p + (size_t)(wv * 8 + n * 2 + kk) * 512 + lane * 8);
    *(v8s*)&lA[0][ar * LAW + ak]     = a0;
    *(v8s*)&lA[0][ar * LAW + ak + 8] = a1v;

    // ---- stage 1: m = relu(A @ W1 + b1) ----
#pragma unroll
    for (int s = 0; s < S; s++) {
        __syncthreads();
        if (s + 1 < S) {
            a0 = (v8s){}; a1v = (v8s){};
            if (aok) {
                a0  = *(const v8s*)(Arow + (s + 1) * 64);
                a1v = *(const v8s*)(Arow + (s + 1) * 64 + 8);
            }
#pragma unroll
            for (int n = 0; n < 4; n++)
#pragma unroll
                for (int kk = 0; kk < 2; kk++)
                    w1nxt[n][kk] = *(const v8s*)(W1p + (size_t)((s + 1) * 32 + wv * 8 + n * 2 + kk) * 512 + lane * 8);
        }
        v8s af[4][2];
#pragma unroll
        for (int m = 0; m < 4; m++)
#pragma unroll
            for (int kk = 0; kk < 2; kk++)
                af[m][kk] = *(const v8s*)&lA[s & 1][(m * 16 + l15) * LAW + kk * 32 + kq * 8];
#pragma unroll
        for (int kk = 0; kk < 2; kk++)
#pragma unroll
            for (int m = 0; m < 4; m++)
#pragma unroll
                for (int n = 0; n < 4; n++)
                    acc[m][n] = __builtin_amdgcn_mfma_f32_16x16x32_bf16(af[m][kk], w1cur[n][kk], acc[m][n], 0, 0, 0);
        if (s + 1 < S) {
            *(v8s*)&lA[(s + 1) & 1][ar * LAW + ak]     = a0;
            *(v8s*)&lA[(s + 1) & 1][ar * LAW + ak + 8] = a1v;
#pragma unroll
            for (int n = 0; n < 4; n++)
#pragma unroll
                for (int kk = 0; kk < 2; kk++)
                    w1cur[n][kk] = w1nxt[n][kk];
        }
    }

    // ---- stage-1 epilogue: bias + relu -> mT (bf16) ----
#pragma unroll
    for (int n = 0; n < 4; n++) {
        const int gc = wv * 64 + n * 16 + l15;
        const float bv = b1[gc];
#pragma unroll
        for (int m = 0; m < 4; m++)
#pragma unroll
            for (int r = 0; r < 4; r++)
                mT[(m * 16 + kq * 4 + r) * MTW + gc] = f2b(fmaxf(acc[m][n][r] + bv, 0.f));
    }
    __syncthreads();  // mT ready

    if constexpr (!HEAD) {
        // ---- stage 2: C = relu(m @ W2 + b2), barrier-free MFMA ----
#pragma unroll
        for (int m = 0; m < 4; m++)
#pragma unroll
            for (int n = 0; n < 4; n++) acc[m][n] = (v4f){0.f, 0.f, 0.f, 0.f};
#pragma unroll
        for (int kh = 0; kh < 2; kh++) {
            v8s w2r[4][4];
#pragma unroll
            for (int n = 0; n < 4; n++)
#pragma unroll
                for (int kk = 0; kk < 4; kk++)
                    w2r[n][kk] = *(const v8s*)(W2p + (size_t)(kh * 64 + wv * 16 + n * 4 + kk) * 512 + lane * 8);
#pragma unroll
            for (int kk = 0; kk < 4; kk++) {
                v8s a2[4];
#pragma unroll
                for (int m = 0; m < 4; m++)
                    a2[m] = *(const v8s*)&mT[(m * 16 + l15) * MTW + kh * 128 + kk * 32 + kq * 8];
#pragma unroll
                for (int m = 0; m < 4; m++)
#pragma unroll
                    for (int n = 0; n < 4; n++)
                        acc[m][n] = __builtin_amdgcn_mfma_f32_16x16x32_bf16(a2[m], w2r[n][kk], acc[m][n], 0, 0, 0);
            }
        }
        __syncthreads();  // all mT reads done before overwrite
        // write result back into mT (bias+relu+bf16)
#pragma unroll
        for (int n = 0; n < 4; n++) {
            const int gc = wv * 64 + n * 16 + l15;
            const float bv = b2[gc];
#pragma unroll
            for (int m = 0; m < 4; m++)
#pragma unroll
                for (int r = 0; r < 4; r++)
                    mT[(m * 16 + kq * 4 + r) * MTW + gc] = f2b(fmaxf(acc[m][n][r] + bv, 0.f));
        }
        __syncthreads();
        // coalesced blit: thread t -> 16B at row i*8+(t>>5), col (t&31)*8
        ushort* C = (ushort*)outp;
        const int brow = tid >> 5, bcol = (tid & 31) * 8;
#pragma unroll
        for (int i = 0; i < 8; i++) {
            const int row = i * 8 + brow;
            if (row0 + row < M) {
                const v8s v = *(const v8s*)&mT[row * MTW + bcol];
                *(v8s*)&C[(size_t)(row0 + row) * 256 + bcol] = v;
            }
        }
    } else {
        // ---- stage 2 head: o = m @ W2b + b2 (16 cols), log_softmax, fp32 out ----
        v4f h = (v4f){0.f, 0.f, 0.f, 0.f};
        v8s w2r[8];
#pragma unroll
        for (int k8 = 0; k8 < 8; k8++)
            w2r[k8] = *(const v8s*)(W2p + (size_t)k8 * 512 + lane * 8);
#pragma unroll
        for (int k8 = 0; k8 < 8; k8++) {
            const v8s a2 = *(const v8s*)&mT[(wv * 16 + l15) * MTW + k8 * 32 + kq * 8];
            h = __builtin_amdgcn_mfma_f32_16x16x32_bf16(a2, w2r[k8], h, 0, 0, 0);
        }
        float* O = (float*)outp;
        const float bv = b2[l15];
#pragma unroll
        for (int r = 0; r < 4; r++) {
            const float v = h[r] + bv;
            float mx = v;
#pragma unroll
            for (int o = 8; o; o >>= 1) mx = fmaxf(mx, __shfl_xor(mx, o, 16));
            const float e = expf(v - mx);
            float sl = e;
#pragma unroll
            for (int o = 8; o; o >>= 1) sl += __shfl_xor(sl, o, 16);
            const int grow = row0 + wv * 16 + kq * 4 + r;
            if (grow < M) O[(size_t)grow * 16 + l15] = (v - mx) - logf(sl);
        }
    }
}

extern "C" void kernel_launch(void* const* d_in, const int* in_sizes, int n_in,
                              void* d_out, int out_size, void* d_ws, size_t ws_size,
                              hipStream_t stream) {
    (void)in_sizes; (void)n_in; (void)out_size; (void)ws_size;
    const float* x   = (const float*)d_in[0];
    const void*  ei  = d_in[1];
    const float* w1a = (const float*)d_in[2];
    const float* b1a = (const float*)d_in[3];
    const float* w2a = (const float*)d_in[4];
    const float* b2a = (const float*)d_in[5];
    const float* w1b = (const float*)d_in[6];
    const float* b1b = (const float*)d_in[7];
    const float* w2b = (const float*)d_in[8];
    const float* b2b = (const float*)d_in[9];
    float* out = (float*)d_out;

    // ws layout (ushort region first, then ints)
    ushort* XB   = (ushort*)d_ws;                 // [NN][128] bf16: x
    ushort* Z1   = XB + (size_t)NN * 128;         // [NN][128] bf16: z1
    ushort* H1   = Z1 + (size_t)NN * 128;         // [NN][256] bf16: h1
    ushort* Z2   = H1 + (size_t)NN * 256;         // [NN][256] bf16: z2
    ushort* W1pa = Z2 + (size_t)NN * 256;         // 128*256 packed
    ushort* W2pa = W1pa + 128 * 256;              // 256*256 packed
    ushort* W1pb = W2pa + 256 * 256;              // 256*256 packed
    ushort* W2hp = W1pb + 256 * 256;              // 16*256 packed
    int* flag    = (int*)(W2hp + 16 * 256);
    int* deg     = flag + 1;                      // NN
    int* rowptr  = deg + NN;                      // NN+1
    int* cursor  = rowptr + NN + 1;               // NN
    int* csr_src = cursor + NN;                   // NE
    int* bsum    = csr_src + NE;                  // SCAN_BLOCKS
    int* boff    = bsum + SCAN_BLOCKS;            // 256

    // ---- init (deg zero + dtype detect), then count+prep merged ----
    init_kernel<<<SCAN_BLOCKS + 1, 256, 0, stream>>>((const int*)ei, flag, deg);
    count_prep_kernel<<<CNTB + XCVT + 656, 256, 0, stream>>>(
        ei, flag, deg, x, XB, w1a, w2a, w1b, w2b, W1pa, W2pa, W1pb, W2hp);

    // ---- CSR scan + fill ----
    block_sum_kernel<<<SCAN_BLOCKS, 256, 0, stream>>>(deg, bsum);
    scan_sums_kernel<<<1, 256, 0, stream>>>(bsum, boff, rowptr);
    block_scan_kernel<<<SCAN_BLOCKS, 256, 0, stream>>>(deg, boff, rowptr, cursor);
    fill_csr_raw_kernel<<<CNTB, 256, 0, stream>>>(ei, flag, cursor, csr_src);

    const int aggBlocks = (NN + 3) / 4;
    const int mlpBlocks = (NN + 63) / 64;

    // ---- conv1: aggregate + fused MLP (z1 -> h1) ----
    aggregate_bf16_kernel<128><<<aggBlocks, 256, 0, stream>>>(XB, Z1, rowptr, csr_src);
    fused_mlp_kernel<128, false><<<mlpBlocks, 256, 0, stream>>>(Z1, W1pa, b1a, W2pa, b2a, H1, NN);

    // ---- conv2: aggregate + fused MLP + head (z2 -> out) ----
    aggregate_bf16_kernel<256><<<aggBlocks, 256, 0, stream>>>(H1, Z2, rowptr, csr_src);
    fused_mlp_kernel<256, true><<<mlpBlocks, 256, 0, stream>>>(Z2, W1pb, b1b, W2hp, b2b, out, NN);
}

// Round 18
// 180.964 us; speedup vs baseline: 1.3822x; 1.0137x over previous
//
#include <hip/hip_runtime.h>

#define NN 50000
#define NE 600000
#define SCAN_BLOCKS 196  // 196*256 = 50176 >= NN

typedef short v8s __attribute__((ext_vector_type(8)));
typedef float v4f __attribute__((ext_vector_type(4)));

#define LAW 72    // lA row stride in shorts: 64 data + 8 pad
#define MTW 264   // mT row stride in shorts: 256 data + 8 pad

__device__ __forceinline__ float uaf(unsigned u) {
    union { unsigned u; float f; } v; v.u = u; return v.f;
}
__device__ __forceinline__ ushort f2b(float f) {
    union { float f; unsigned u; } v; v.f = f;
    unsigned r = v.u + 0x7FFFu + ((v.u >> 16) & 1u);  // RNE
    return (ushort)(r >> 16);
}

// ---------- init: zero deg (blocks 0..195) + edge-dtype detect (block 196) ----------
__global__ __launch_bounds__(256) void init_kernel(const int* __restrict__ raw,
                                                    int* __restrict__ flag,
                                                    int* __restrict__ deg) {
    if (blockIdx.x < SCAN_BLOCKS) {
        const int i = blockIdx.x * 256 + threadIdx.x;
        if (i < NN) deg[i] = 0;
    } else {
        __shared__ int cnt;
        if (threadIdx.x == 0) cnt = 0;
        __syncthreads();
        int c = 0;
        for (int i = threadIdx.x; i < 2048; i += 256)
            if (raw[2 * i + 1] != 0) c++;
        atomicAdd(&cnt, c);
        __syncthreads();
        if (threadIdx.x == 0) *flag = (cnt > 10) ? 1 : 0;  // 1 => int32 layout
    }
}

// ---------- merged: degree count (2 edges/thread) + x cvt + weight packing ----------
#define CNTB 1172                  // ceil(NE/2/256)
#define XCVT (NN * 128 / 4 / 256)  // 6250
__device__ __forceinline__ void pack_w1_elem(const float* in, ushort* out, int o) {
    int j = o & 7, lane = (o >> 3) & 63, f = o >> 9;
    int kk = f & 1, n = (f >> 1) & 3, wv = (f >> 3) & 3, s = f >> 5;
    int k = s * 64 + kk * 32 + (lane >> 4) * 8 + j;
    int col = wv * 64 + n * 16 + (lane & 15);
    out[o] = f2b(in[(size_t)k * 256 + col]);
}
__global__ __launch_bounds__(256) void count_prep_kernel(const void* __restrict__ raw,
                                                          const int* __restrict__ flag,
                                                          int* __restrict__ deg,
                                                          const float* __restrict__ x,
                                                          ushort* __restrict__ XB,
                                                          const float* __restrict__ w1a,
                                                          const float* __restrict__ w2a,
                                                          const float* __restrict__ w1b,
                                                          const float* __restrict__ wh,
                                                          ushort* __restrict__ W1pa,
                                                          ushort* __restrict__ W2pa,
                                                          ushort* __restrict__ W1pb,
                                                          ushort* __restrict__ W2hp) {
    const int b = blockIdx.x;
    if (b < CNTB) {
        const int e2 = b * 256 + threadIdx.x;      // handles edges 2*e2, 2*e2+1
        const int e = e2 * 2;
        if (e >= NE) return;
        int d0, d1;
        if (*flag) {
            const int2 d = *(const int2*)&((const int*)raw)[NE + e];
            d0 = d.x; d1 = d.y;
        } else {
            const longlong2 d = *(const longlong2*)&((const long long*)raw)[NE + e];
            d0 = (int)d.x; d1 = (int)d.y;
        }
        atomicAdd(&deg[d0], 1);
        if (e + 1 < NE) atomicAdd(&deg[d1], 1);
    } else if (b < CNTB + XCVT) {
        const int i = (b - CNTB) * 256 + threadIdx.x;
        const float4 v = *(const float4*)&x[(size_t)i * 4];
        ushort4 o;
        o.x = f2b(v.x); o.y = f2b(v.y); o.z = f2b(v.z); o.w = f2b(v.w);
        *(ushort4*)&XB[(size_t)i * 4] = o;
    } else if (b < CNTB + XCVT + 128) {
        pack_w1_elem(w1a, W1pa, (b - CNTB - XCVT) * 256 + threadIdx.x);
    } else if (b < CNTB + XCVT + 384) {
        int o = (b - CNTB - XCVT - 128) * 256 + threadIdx.x;
        int j = o & 7, lane = (o >> 3) & 63, f = o >> 9;
        int kk = f & 3, n = (f >> 2) & 3, wv = (f >> 4) & 3, kh = f >> 6;
        int k = kh * 128 + kk * 32 + (lane >> 4) * 8 + j;
        int col = wv * 64 + n * 16 + (lane & 15);
        W2pa[o] = f2b(w2a[(size_t)k * 256 + col]);
    } else if (b < CNTB + XCVT + 640) {
        pack_w1_elem(w1b, W1pb, (b - CNTB - XCVT - 384) * 256 + threadIdx.x);
    } else {
        int o = (b - CNTB - XCVT - 640) * 256 + threadIdx.x;
        int j = o & 7, lane = (o >> 3) & 63, k8 = o >> 9;
        int k = k8 * 32 + (lane >> 4) * 8 + j;
        int col = lane & 15;
        W2hp[o] = f2b(wh[(size_t)k * 16 + col]);
    }
}

// ---------- scan pass 1: per-block degree sums ----------
__global__ __launch_bounds__(256) void block_sum_kernel(const int* __restrict__ deg,
                                                         int* __restrict__ bsum) {
    const int i = blockIdx.x * 256 + threadIdx.x;
    int v = (i < NN) ? deg[i] : 0;
#pragma unroll
    for (int o = 32; o; o >>= 1) v += __shfl_down(v, o, 64);
    __shared__ int ws[4];
    if ((threadIdx.x & 63) == 0) ws[threadIdx.x >> 6] = v;
    __syncthreads();
    if (threadIdx.x == 0) bsum[blockIdx.x] = ws[0] + ws[1] + ws[2] + ws[3];
}

// ---------- scan pass 2 (merged): each block redundantly scans bsum (196 vals)
// in LDS to get its own offset, then does the local 256-scan -> rowptr/cursor.
// Block 0 also writes rowptr[NN] = total. Replaces the old scan_sums dispatch.
__global__ __launch_bounds__(256) void block_scan_kernel(const int* __restrict__ deg,
                                                          const int* __restrict__ bsum,
                                                          int* __restrict__ rowptr,
                                                          int* __restrict__ cursor) {
    __shared__ int tmp[256];
    const int t = threadIdx.x;
    const int bv = (t < SCAN_BLOCKS) ? bsum[t] : 0;
    tmp[t] = bv;
    __syncthreads();
#pragma unroll
    for (int off = 1; off < 256; off <<= 1) {
        int u = (t >= off) ? tmp[t - off] : 0;
        __syncthreads();
        tmp[t] += u;
        __syncthreads();
    }
    // tmp = inclusive scan of bsum; block offset = exclusive prefix
    __shared__ int blockOff;
    if (t == 0) blockOff = (blockIdx.x == 0) ? 0 : tmp[blockIdx.x - 1];
    if (blockIdx.x == 0 && t == 255) rowptr[NN] = tmp[255];  // grand total
    __syncthreads();

    const int i = blockIdx.x * 256 + t;
    const int lane = t & 63, w = t >> 6;
    const int v = (i < NN) ? deg[i] : 0;
    int s = v;
#pragma unroll
    for (int o = 1; o < 64; o <<= 1) {
        int u = __shfl_up(s, o, 64);
        if (lane >= o) s += u;
    }
    __shared__ int wsum[4];
    if (lane == 63) wsum[w] = s;
    __syncthreads();
    int wpre = 0;
    for (int k = 0; k < w; k++) wpre += wsum[k];
    const int excl = blockOff + wpre + s - v;
    if (i < NN) {
        rowptr[i] = excl;
        cursor[i] = excl;
    }
}

// CSR fill from raw edges, 2 edges/thread
__global__ __launch_bounds__(256) void fill_csr_raw_kernel(const void* __restrict__ raw,
                                                            const int* __restrict__ flag,
                                                            int* __restrict__ cursor,
                                                            int* __restrict__ csr_src) {
    const int e2 = blockIdx.x * 256 + threadIdx.x;
    const int e = e2 * 2;
    if (e >= NE) return;
    int s0, s1, d0, d1;
    if (*flag) {
        const int2 s = *(const int2*)&((const int*)raw)[e];
        const int2 d = *(const int2*)&((const int*)raw)[NE + e];
        s0 = s.x; s1 = s.y; d0 = d.x; d1 = d.y;
    } else {
        const longlong2 s = *(const longlong2*)&((const long long*)raw)[e];
        const longlong2 d = *(const longlong2*)&((const long long*)raw)[NE + e];
        s0 = (int)s.x; s1 = (int)s.y; d0 = (int)d.x; d1 = (int)d.y;
    }
    int pos = atomicAdd(&cursor[d0], 1);
    csr_src[pos] = s0;
    if (e + 1 < NE) {
        pos = atomicAdd(&cursor[d1], 1);
        csr_src[pos] = s1;
    }
}

// ---------- gather-aggregate v2: scalar index path, 8 gathers in flight ----------
template <int D>
__global__ __launch_bounds__(256) void aggregate_bf16_kernel(const ushort* __restrict__ feat,
                                                              ushort* __restrict__ z,
                                                              const int* __restrict__ rowptr,
                                                              const int* __restrict__ csr_src) {
    const int node = __builtin_amdgcn_readfirstlane(blockIdx.x * 4 + (threadIdx.x >> 6));
    const int lane = threadIdx.x & 63;
    if (node >= NN) return;
    const int rbeg = rowptr[node];
    const int rend = rowptr[node + 1];

    if constexpr (D == 256) {
        const size_t base = (size_t)node * 256 + lane * 4;
        const uint2 sv = *(const uint2*)&feat[base];
        float a0 = uaf(sv.x << 16), a1 = uaf(sv.x & 0xFFFF0000u);
        float a2 = uaf(sv.y << 16), a3 = uaf(sv.y & 0xFFFF0000u);
        int j = rbeg;
        for (; j + 7 < rend; j += 8) {
            uint2 v[8];
#pragma unroll
            for (int q = 0; q < 8; q++)
                v[q] = *(const uint2*)&feat[(size_t)csr_src[j + q] * 256 + lane * 4];
#pragma unroll
            for (int q = 0; q < 8; q++) {
                a0 += uaf(v[q].x << 16); a1 += uaf(v[q].x & 0xFFFF0000u);
                a2 += uaf(v[q].y << 16); a3 += uaf(v[q].y & 0xFFFF0000u);
            }
        }
        for (; j + 3 < rend; j += 4) {
            uint2 v[4];
#pragma unroll
            for (int q = 0; q < 4; q++)
                v[q] = *(const uint2*)&feat[(size_t)csr_src[j + q] * 256 + lane * 4];
#pragma unroll
            for (int q = 0; q < 4; q++) {
                a0 += uaf(v[q].x << 16); a1 += uaf(v[q].x & 0xFFFF0000u);
                a2 += uaf(v[q].y << 16); a3 += uaf(v[q].y & 0xFFFF0000u);
            }
        }
        for (; j < rend; j++) {
            const uint2 v = *(const uint2*)&feat[(size_t)csr_src[j] * 256 + lane * 4];
            a0 += uaf(v.x << 16); a1 += uaf(v.x & 0xFFFF0000u);
            a2 += uaf(v.y << 16); a3 += uaf(v.y & 0xFFFF0000u);
        }
        uint2 o;
        o.x = (uint)f2b(a0) | ((uint)f2b(a1) << 16);
        o.y = (uint)f2b(a2) | ((uint)f2b(a3) << 16);
        *(uint2*)&z[base] = o;
    } else {  // D == 128
        const size_t base = (size_t)node * 128 + lane * 2;
        const uint sv = *(const uint*)&feat[base];
        float a0 = uaf(sv << 16), a1 = uaf(sv & 0xFFFF0000u);
        int j = rbeg;
        for (; j + 7 < rend; j += 8) {
            uint v[8];
#pragma unroll
            for (int q = 0; q < 8; q++)
                v[q] = *(const uint*)&feat[(size_t)csr_src[j + q] * 128 + lane * 2];
#pragma unroll
            for (int q = 0; q < 8; q++) {
                a0 += uaf(v[q] << 16); a1 += uaf(v[q] & 0xFFFF0000u);
            }
        }
        for (; j + 3 < rend; j += 4) {
            uint v[4];
#pragma unroll
            for (int q = 0; q < 4; q++)
                v[q] = *(const uint*)&feat[(size_t)csr_src[j + q] * 128 + lane * 2];
#pragma unroll
            for (int q = 0; q < 4; q++) {
                a0 += uaf(v[q] << 16); a1 += uaf(v[q] & 0xFFFF0000u);
            }
        }
        for (; j < rend; j++) {
            const uint v = *(const uint*)&feat[(size_t)csr_src[j] * 128 + lane * 2];
            a0 += uaf(v << 16); a1 += uaf(v & 0xFFFF0000u);
        }
        *(uint*)&z[base] = (uint)f2b(a0) | ((uint)f2b(a1) << 16);
    }
}

// ---------- fused 2-layer MLP v5: frag-major W + blit epilogue (round-12/13) ----------
template <int K1, bool HEAD>
__global__ __launch_bounds__(256) void fused_mlp_kernel(const ushort* __restrict__ A,
                                                         const ushort* __restrict__ W1p,
                                                         const float* __restrict__ b1,
                                                         const ushort* __restrict__ W2p,
                                                         const float* __restrict__ b2,
                                                         void* __restrict__ outp, int M) {
    constexpr int S = K1 / 64;          // stage-1 k-steps
    __shared__ ushort lA[2][64 * LAW];  // 18.4 KB dbuf A k-tile [64][64]
    __shared__ ushort mT[64 * MTW];     // 33.8 KB stage-1 output [64][256] bf16
    const int tid = threadIdx.x;
    const int lane = tid & 63;
    const int wv = tid >> 6;
    const int row0 = blockIdx.x * 64;
    const int l15 = lane & 15;
    const int kq = lane >> 4;
    const int ar = tid >> 2, ak = (tid & 3) * 16;  // A staging: row, k-chunk

    const bool aok = (row0 + ar) < M;
    const ushort* Arow = A + (size_t)(row0 + ar) * K1 + ak;

    v4f acc[4][4];
#pragma unroll
    for (int m = 0; m < 4; m++)
#pragma unroll
        for (int n = 0; n < 4; n++) acc[m][n] = (v4f){0.f, 0.f, 0.f, 0.f};

    v8s a0 = {}, a1v = {};
    v8s w1cur[4][2], w1nxt[4][2];

    // ---- prologue: step-0 A + W1 (contiguous frag loads) ----
    if (aok) { a0 = *(const v8s*)Arow; a1v = *(const v8s*)(Arow + 8); }
#pragma unroll
    for (int n = 0; n < 4; n++)
#pragma unroll
        for (int kk = 0; kk < 2; kk++)
            w1cur[n][kk] = *(const v8s*)(W1p + (size_t)(wv * 8 + n * 2 + kk) * 512 + lane * 8);
    *(v8s*)&lA[0][ar * LAW + ak]     = a0;
    *(v8s*)&lA[0][ar * LAW + ak + 8] = a1v;

    // ---- stage 1: m = relu(A @ W1 + b1) ----
#pragma unroll
    for (int s = 0; s < S; s++) {
        __syncthreads();
        if (s + 1 < S) {
            a0 = (v8s){}; a1v = (v8s){};
            if (aok) {
                a0  = *(const v8s*)(Arow + (s + 1) * 64);
                a1v = *(const v8s*)(Arow + (s + 1) * 64 + 8);
            }
#pragma unroll
            for (int n = 0; n < 4; n++)
#pragma unroll
                for (int kk = 0; kk < 2; kk++)
                    w1nxt[n][kk] = *(const v8s*)(W1p + (size_t)((s + 1) * 32 + wv * 8 + n * 2 + kk) * 512 + lane * 8);
        }
        v8s af[4][2];
#pragma unroll
        for (int m = 0; m < 4; m++)
#pragma unroll
            for (int kk = 0; kk < 2; kk++)
                af[m][kk] = *(const v8s*)&lA[s & 1][(m * 16 + l15) * LAW + kk * 32 + kq * 8];
#pragma unroll
        for (int kk = 0; kk < 2; kk++)
#pragma unroll
            for (int m = 0; m < 4; m++)
#pragma unroll
                for (int n = 0; n < 4; n++)
                    acc[m][n] = __builtin_amdgcn_mfma_f32_16x16x32_bf16(af[m][kk], w1cur[n][kk], acc[m][n], 0, 0, 0);
        if (s + 1 < S) {
            *(v8s*)&lA[(s + 1) & 1][ar * LAW + ak]     = a0;
            *(v8s*)&lA[(s + 1) & 1][ar * LAW + ak + 8] = a1v;
#pragma unroll
            for (int n = 0; n < 4; n++)
#pragma unroll
                for (int kk = 0; kk < 2; kk++)
                    w1cur[n][kk] = w1nxt[n][kk];
        }
    }

    // ---- stage-1 epilogue: bias + relu -> mT (bf16) ----
#pragma unroll
    for (int n = 0; n < 4; n++) {
        const int gc = wv * 64 + n * 16 + l15;
        const float bv = b1[gc];
#pragma unroll
        for (int m = 0; m < 4; m++)
#pragma unroll
            for (int r = 0; r < 4; r++)
                mT[(m * 16 + kq * 4 + r) * MTW + gc] = f2b(fmaxf(acc[m][n][r] + bv, 0.f));
    }
    __syncthreads();  // mT ready

    if constexpr (!HEAD) {
        // ---- stage 2: C = relu(m @ W2 + b2), barrier-free MFMA ----
#pragma unroll
        for (int m = 0; m < 4; m++)
#pragma unroll
            for (int n = 0; n < 4; n++) acc[m][n] = (v4f){0.f, 0.f, 0.f, 0.f};
#pragma unroll
        for (int kh = 0; kh < 2; kh++) {
            v8s w2r[4][4];
#pragma unroll
            for (int n = 0; n < 4; n++)
#pragma unroll
                for (int kk = 0; kk < 4; kk++)
                    w2r[n][kk] = *(const v8s*)(W2p + (size_t)(kh * 64 + wv * 16 + n * 4 + kk) * 512 + lane * 8);
#pragma unroll
            for (int kk = 0; kk < 4; kk++) {
                v8s a2[4];
#pragma unroll
                for (int m = 0; m < 4; m++)
                    a2[m] = *(const v8s*)&mT[(m * 16 + l15) * MTW + kh * 128 + kk * 32 + kq * 8];
#pragma unroll
                for (int m = 0; m < 4; m++)
#pragma unroll
                    for (int n = 0; n < 4; n++)
                        acc[m][n] = __builtin_amdgcn_mfma_f32_16x16x32_bf16(a2[m], w2r[n][kk], acc[m][n], 0, 0, 0);
            }
        }
        __syncthreads();  // all mT reads done before overwrite
        // write result back into mT (bias+relu+bf16)
#pragma unroll
        for (int n = 0; n < 4; n++) {
            const int gc = wv * 64 + n * 16 + l15;
            const float bv = b2[gc];
#pragma unroll
            for (int m = 0; m < 4; m++)
#pragma unroll
                for (int r = 0; r < 4; r++)
                    mT[(m * 16 + kq * 4 + r) * MTW + gc] = f2b(fmaxf(acc[m][n][r] + bv, 0.f));
        }
        __syncthreads();
        // coalesced blit: thread t -> 16B at row i*8+(t>>5), col (t&31)*8
        ushort* C = (ushort*)outp;
        const int brow = tid >> 5, bcol = (tid & 31) * 8;
#pragma unroll
        for (int i = 0; i < 8; i++) {
            const int row = i * 8 + brow;
            if (row0 + row < M) {
                const v8s v = *(const v8s*)&mT[row * MTW + bcol];
                *(v8s*)&C[(size_t)(row0 + row) * 256 + bcol] = v;
            }
        }
    } else {
        // ---- stage 2 head: o = m @ W2b + b2 (16 cols), log_softmax, fp32 out ----
        v4f h = (v4f){0.f, 0.f, 0.f, 0.f};
        v8s w2r[8];
#pragma unroll
        for (int k8 = 0; k8 < 8; k8++)
            w2r[k8] = *(const v8s*)(W2p + (size_t)k8 * 512 + lane * 8);
#pragma unroll
        for (int k8 = 0; k8 < 8; k8++) {
            const v8s a2 = *(const v8s*)&mT[(wv * 16 + l15) * MTW + k8 * 32 + kq * 8];
            h = __builtin_amdgcn_mfma_f32_16x16x32_bf16(a2, w2r[k8], h, 0, 0, 0);
        }
        float* O = (float*)outp;
        const float bv = b2[l15];
#pragma unroll
        for (int r = 0; r < 4; r++) {
            const float v = h[r] + bv;
            float mx = v;
#pragma unroll
            for (int o = 8; o; o >>= 1) mx = fmaxf(mx, __shfl_xor(mx, o, 16));
            const float e = expf(v - mx);
            float sl = e;
#pragma unroll
            for (int o = 8; o; o >>= 1) sl += __shfl_xor(sl, o, 16);
            const int grow = row0 + wv * 16 + kq * 4 + r;
            if (grow < M) O[(size_t)grow * 16 + l15] = (v - mx) - logf(sl);
        }
    }
}

extern "C" void kernel_launch(void* const* d_in, const int* in_sizes, int n_in,
                              void* d_out, int out_size, void* d_ws, size_t ws_size,
                              hipStream_t stream) {
    (void)in_sizes; (void)n_in; (void)out_size; (void)ws_size;
    const float* x   = (const float*)d_in[0];
    const void*  ei  = d_in[1];
    const float* w1a = (const float*)d_in[2];
    const float* b1a = (const float*)d_in[3];
    const float* w2a = (const float*)d_in[4];
    const float* b2a = (const float*)d_in[5];
    const float* w1b = (const float*)d_in[6];
    const float* b1b = (const float*)d_in[7];
    const float* w2b = (const float*)d_in[8];
    const float* b2b = (const float*)d_in[9];
    float* out = (float*)d_out;

    // ws layout (ushort region first, then ints)
    ushort* XB   = (ushort*)d_ws;                 // [NN][128] bf16: x
    ushort* Z1   = XB + (size_t)NN * 128;         // [NN][128] bf16: z1
    ushort* H1   = Z1 + (size_t)NN * 128;         // [NN][256] bf16: h1
    ushort* Z2   = H1 + (size_t)NN * 256;         // [NN][256] bf16: z2
    ushort* W1pa = Z2 + (size_t)NN * 256;         // 128*256 packed
    ushort* W2pa = W1pa + 128 * 256;              // 256*256 packed
    ushort* W1pb = W2pa + 256 * 256;              // 256*256 packed
    ushort* W2hp = W1pb + 256 * 256;              // 16*256 packed
    int* flag    = (int*)(W2hp + 16 * 256);
    int* deg     = flag + 1;                      // NN
    int* rowptr  = deg + NN;                      // NN+1
    int* cursor  = rowptr + NN + 1;               // NN
    int* csr_src = cursor + NN;                   // NE
    int* bsum    = csr_src + NE;                  // SCAN_BLOCKS

    // ---- init (deg zero + dtype detect), then count+prep merged ----
    init_kernel<<<SCAN_BLOCKS + 1, 256, 0, stream>>>((const int*)ei, flag, deg);
    count_prep_kernel<<<CNTB + XCVT + 656, 256, 0, stream>>>(
        ei, flag, deg, x, XB, w1a, w2a, w1b, w2b, W1pa, W2pa, W1pb, W2hp);

    // ---- CSR scan (2 dispatches) + fill ----
    block_sum_kernel<<<SCAN_BLOCKS, 256, 0, stream>>>(deg, bsum);
    block_scan_kernel<<<SCAN_BLOCKS, 256, 0, stream>>>(deg, bsum, rowptr, cursor);
    fill_csr_raw_kernel<<<CNTB, 256, 0, stream>>>(ei, flag, cursor, csr_src);

    const int aggBlocks = (NN + 3) / 4;
    const int mlpBlocks = (NN + 63) / 64;

    // ---- conv1: aggregate + fused MLP (z1 -> h1) ----
    aggregate_bf16_kernel<128><<<aggBlocks, 256, 0, stream>>>(XB, Z1, rowptr, csr_src);
    fused_mlp_kernel<128, false><<<mlpBlocks, 256, 0, stream>>>(Z1, W1pa, b1a, W2pa, b2a, H1, NN);

    // ---- conv2: aggregate + fused MLP + head (z2 -> out) ----
    aggregate_bf16_kernel<256><<<aggBlocks, 256, 0, stream>>>(H1, Z2, rowptr, csr_src);
    fused_mlp_kernel<256, true><<<mlpBlocks, 256, 0, stream>>>(Z2, W1pb, b1b, W2hp, b2b, out, NN);
}